// Round 7
// baseline (526.655 us; speedup 1.0000x reference)
//
#include <hip/hip_runtime.h>

typedef unsigned short u16;
typedef __attribute__((ext_vector_type(8))) short short8;
typedef __attribute__((ext_vector_type(4))) short short4v;
typedef __attribute__((ext_vector_type(4))) float f32x4;

#define DEV static __device__ __forceinline__

DEV float bf2f(u16 h) {
    union { unsigned int u; float f; } v; v.u = ((unsigned int)h) << 16; return v.f;
}
DEV u16 f2bf(float f) {
    union { float f; unsigned int u; } v; v.f = f;
    unsigned int r = (v.u + 0x7fff + ((v.u >> 16) & 1)) >> 16;
    return (u16)r;
}
DEV float ldx(const void* p, size_t i, int f32) {
    return f32 ? ((const float*)p)[i] : bf2f(((const u16*)p)[i]);
}

// 0.125 (HD^-0.5) * log2(e): Q pre-scaled so attention softmax uses exp2 directly.
#define QSCL 0.18033688011112042f

#define GLD16(g, l) __builtin_amdgcn_global_load_lds( \
    (const __attribute__((address_space(1))) void*)(g), \
    (__attribute__((address_space(3))) void*)(l), 16, 0, 0)

#define STAGE(P, pf32, eoff, dst8) do {                                        \
    if (!(pf32)) { GLD16(((const u16*)(P)) + (eoff), (dst8)); }                \
    else {                                                                     \
        const float* _p = ((const float*)(P)) + (eoff);                        \
        f32x4 _a = *(const f32x4*)_p, _b = *(const f32x4*)(_p + 4);            \
        short8 _s;                                                             \
        _s[0]=(short)f2bf(_a[0]); _s[1]=(short)f2bf(_a[1]);                    \
        _s[2]=(short)f2bf(_a[2]); _s[3]=(short)f2bf(_a[3]);                    \
        _s[4]=(short)f2bf(_b[0]); _s[5]=(short)f2bf(_b[1]);                    \
        _s[6]=(short)f2bf(_b[2]); _s[7]=(short)f2bf(_b[3]);                    \
        *(short8*)(dst8) = _s;                                                 \
    } } while (0)

// ---------------------------------------------------------------------------
// Probe: flags[0]=1 -> inputs fp32; flags[1]=1 -> mask is bool bytes.
// ---------------------------------------------------------------------------
__global__ __launch_bounds__(64) void probe_kernel(
    const void* __restrict__ x, const void* __restrict__ pad,
    int* __restrict__ flags, int* __restrict__ flagsA)
{
    const int lane = threadIdx.x;
    const u16* xu = (const u16*)x;
    const unsigned int e = (xu[lane * 2] >> 7) & 0xFF;
    const int sane = (e >= 0x70 && e <= 0x8F) ? 1 : 0;
    unsigned long long m = __ballot(sane);
    const int f32 = (__popcll(m) < 32) ? 1 : 0;

    const unsigned int* pi = (const unsigned int*)pad;
    int bytes = 0;
#pragma unroll
    for (int j = 0; j < 6; j++) {
        unsigned int v = pi[128 + j * 64 + lane];
        if (v > 1u) bytes = 1;
    }
    m = __ballot(bytes);
    if (lane == 0) {
        flags[0] = f32; flags[1] = (m != 0ULL) ? 1 : 0;
        flagsA[0] = 0;  flagsA[1] = 0;
    }
}

__global__ __launch_bounds__(256) void conv4(
    const void* __restrict__ src, u16* __restrict__ dst, int n4,
    const int* __restrict__ flags)
{
    const int i = blockIdx.x * 256 + threadIdx.x;
    if (i >= n4) return;
    if (flags[0]) {
        f32x4 v = ((const f32x4*)src)[i];
        short4v s;
        s[0] = (short)f2bf(v[0]); s[1] = (short)f2bf(v[1]);
        s[2] = (short)f2bf(v[2]); s[3] = (short)f2bf(v[3]);
        ((short4v*)dst)[i] = s;
    } else {
        ((short4v*)dst)[i] = ((const short4v*)src)[i];
    }
}

__global__ __launch_bounds__(256) void mask_to_bias(
    const void* __restrict__ pad, float* __restrict__ out,
    const int* __restrict__ flags)
{
    const int i = blockIdx.x * 256 + threadIdx.x;
    const int mv = flags[1] ? (int)((const unsigned char*)pad)[i]
                            : ((const int*)pad)[i];
    out[i] = mv ? -1e30f : 0.0f;
}

// ---------------------------------------------------------------------------
// Shared GEMM core: 128x128 tile, BK=32, 256 threads (4 waves, 4x4 mfma each).
// (retained for tier C)
// ---------------------------------------------------------------------------
#define GEMM_CORE(Av, ASEL, a_row0, Wv, w_off, ldw, K)                        \
    __shared__ __align__(16) u16 As[128 * 32];                                \
    __shared__ __align__(16) u16 Bs[128 * 32];                                \
    const int inf32 = flags[0];                                               \
    const int af32  = (ASEL) ? inf32 : 0;                                     \
    const int tid  = threadIdx.x;                                             \
    const int lane = tid & 63;                                                \
    const int wave = tid >> 6;                                                \
    const int lc   = lane & 15;                                               \
    const int quad = lane >> 4;                                               \
    const int m0 = blockIdx.x * 128;                                          \
    const int n0 = blockIdx.y * 128;                                          \
    const int wm = (wave >> 1) * 64;                                          \
    const int wn = (wave & 1) * 64;                                           \
    const int r0 = tid >> 2;                                                  \
    const int ko = (tid & 3) * 8;                                             \
    f32x4 acc[4][4] = {};                                                     \
    for (int k0 = 0; k0 < (K); k0 += 32) {                                    \
        STAGE(Av, af32, ((size_t)(a_row0) + m0 + r0) * (K) + k0 + ko,         \
              &As[tid * 8]);                                                  \
        STAGE(Av, af32, ((size_t)(a_row0) + m0 + r0 + 64) * (K) + k0 + ko,    \
              &As[2048 + tid * 8]);                                           \
        STAGE(Wv, inf32, (size_t)(w_off) + (size_t)(n0 + r0) * (ldw) + k0 + ko,\
              &Bs[tid * 8]);                                                  \
        STAGE(Wv, inf32, (size_t)(w_off) + (size_t)(n0 + r0 + 64) * (ldw) + k0 + ko,\
              &Bs[2048 + tid * 8]);                                           \
        __syncthreads();                                                      \
        short8 afr[4], bfr[4];                                                \
        const int qd = quad * 8;                                              \
        _Pragma("unroll")                                                     \
        for (int mt = 0; mt < 4; mt++)                                        \
            afr[mt] = *(const short8*)&As[(wm + mt * 16 + lc) * 32 + qd];     \
        _Pragma("unroll")                                                     \
        for (int nt = 0; nt < 4; nt++)                                        \
            bfr[nt] = *(const short8*)&Bs[(wn + nt * 16 + lc) * 32 + qd];     \
        _Pragma("unroll")                                                     \
        for (int mt = 0; mt < 4; mt++)                                        \
            _Pragma("unroll")                                                 \
            for (int nt = 0; nt < 4; nt++)                                    \
                acc[mt][nt] = __builtin_amdgcn_mfma_f32_16x16x32_bf16(        \
                    afr[mt], bfr[nt], acc[mt][nt], 0, 0, 0);                  \
        __syncthreads();                                                      \
    }                                                                         \
    const int ce0 = n0 + wn + lc;                                             \
    const int re0 = m0 + wm + quad * 4;

// Generic GEMM: C = A @ W^T + bias.  EPI: 0 bias, 1 +resid, 2 +relu.
template<int EPI>
__global__ __launch_bounds__(256, 2) void gemm_bt(
    const void* __restrict__ A, int a_sel, long a_row0,
    const void* __restrict__ W, long w_off,
    const void* __restrict__ bias, long b_off,
    const void* __restrict__ resid, int r_sel, long r_row0,
    u16* __restrict__ C, long c_row0,
    int N, int K, int ldw, const int* __restrict__ flags)
{
    GEMM_CORE(A, a_sel, a_row0, W, w_off, ldw, K)
    const int rf32 = r_sel ? inf32 : 0;
#pragma unroll
    for (int mt = 0; mt < 4; mt++) {
#pragma unroll
        for (int nt = 0; nt < 4; nt++) {
            const int c = ce0 + nt * 16;
            const float bv = ldx(bias, (size_t)b_off + c, inf32);
#pragma unroll
            for (int i = 0; i < 4; i++) {
                const int r = re0 + mt * 16 + i;
                float v = acc[mt][nt][i] + bv;
                if (EPI == 1)
                    v += ldx(resid, ((size_t)r_row0 + r) * N + c, rf32);
                if (EPI == 2) v = fmaxf(v, 0.0f);
                C[((size_t)c_row0 + r) * N + c] = f2bf(v);
            }
        }
    }
}

// QKV GEMM (tier C): N=3072 split epilogue on the 128x128 core.
__global__ __launch_bounds__(256, 2) void gemm_qkv(
    const void* __restrict__ A, long a_row0,
    const void* __restrict__ W, const void* __restrict__ bias,
    u16* __restrict__ Qo, u16* __restrict__ Ko, u16* __restrict__ Vt,
    const int* __restrict__ flags)
{
    GEMM_CORE(A, 1, a_row0, W, 0, 1024, 1024)
    if (n0 < 1024) {
#pragma unroll
        for (int mt = 0; mt < 4; mt++)
#pragma unroll
            for (int nt = 0; nt < 4; nt++) {
                const int c = ce0 + nt * 16;
                const float bv = ldx(bias, c, inf32);
#pragma unroll
                for (int i = 0; i < 4; i++) {
                    const int r = re0 + mt * 16 + i;
                    Qo[((size_t)a_row0 + r) * 1024 + c] =
                        f2bf((acc[mt][nt][i] + bv) * QSCL);
                }
            }
    } else if (n0 < 2048) {
#pragma unroll
        for (int mt = 0; mt < 4; mt++)
#pragma unroll
            for (int nt = 0; nt < 4; nt++) {
                const int c = ce0 + nt * 16;
                const float bv = ldx(bias, c, inf32);
#pragma unroll
                for (int i = 0; i < 4; i++) {
                    const int r = re0 + mt * 16 + i;
                    Ko[(size_t)r * 1024 + (c - 1024)] = f2bf(acc[mt][nt][i] + bv);
                }
            }
    } else {
#pragma unroll
        for (int mt = 0; mt < 4; mt++)
#pragma unroll
            for (int nt = 0; nt < 4; nt++) {
                const int c = ce0 + nt * 16;
                const float bv = ldx(bias, c, inf32);
                const int cv = c - 2048;
                const int hh = cv >> 6, d = cv & 63;
                const int rb = re0 + mt * 16;
                const int bl = rb >> 10, t = rb & 1023;
                short4v pk;
#pragma unroll
                for (int i = 0; i < 4; i++)
                    pk[i] = (short)f2bf(acc[mt][nt][i] + bv);
                *(short4v*)&Vt[((size_t)(bl * 16 + hh) * 64 + d) * 1024 + t] = pk;
            }
    }
}

// fc2 K-chunk accumulating into fp32 (tier C only)
__global__ __launch_bounds__(256, 2) void gemm_accf32(
    const void* __restrict__ A, const void* __restrict__ W, long w_off,
    const void* __restrict__ bias, const u16* __restrict__ resid, long r_row0,
    float* __restrict__ C, int ldw, int init, const int* __restrict__ flags)
{
    GEMM_CORE(A, 0, 0, W, w_off, ldw, 1024)
#pragma unroll
    for (int mt = 0; mt < 4; mt++) {
#pragma unroll
        for (int nt = 0; nt < 4; nt++) {
            const int c = ce0 + nt * 16;
            const float bv = ldx(bias, c, inf32);
#pragma unroll
            for (int i = 0; i < 4; i++) {
                const int r = re0 + mt * 16 + i;
                float v = acc[mt][nt][i];
                if (init) v += bv + bf2f(resid[((size_t)r_row0 + r) * 1024 + c]);
                else      v += C[(size_t)r * 1024 + c];
                C[(size_t)r * 1024 + c] = v;
            }
        }
    }
}

// ---------------------------------------------------------------------------
// gemm8: 128x256 tile, BK=64, 512 threads = 8 waves (2M x 4N), per-wave 64x64.
// Triple-buffered, vmcnt(6). (retained for out-proj / fc2 where the 256-tile
// grid would leave half the device idle)
// ---------------------------------------------------------------------------
#define GEMM8_PRE(Ag_, Wg_, Kg_)                                              \
    __shared__ __align__(16) u16 Ab[3][128 * 64];                             \
    __shared__ __align__(16) u16 Bb[3][256 * 64];                             \
    const u16* Ag = (Ag_); const u16* Wg = (Wg_); const int Kg = (Kg_);       \
    const int tid  = threadIdx.x;                                             \
    const int lane = tid & 63;                                                \
    const int lc   = lane & 15;                                               \
    const int quad = lane >> 4;                                               \
    const int w    = tid >> 6;                                                \
    const int wr   = w >> 2;                                                  \
    const int wc   = w & 3;                                                   \
    const int m0 = blockIdx.x * 128;                                          \
    const int n0 = blockIdx.y * 256;                                          \
    const int srow = tid >> 3;                                                \
    const int scol = (((tid & 7) ^ (srow & 7)) << 3);                         \
    const int sw0 = (((quad) ^ (lc & 7)) << 3);                               \
    const int sw1 = sw0 ^ 32;                                                 \
    f32x4 acc[4][4] = {};                                                     \
    short8 af[4], bf[4];

#define SA8(buf, kk) do {                                                     \
    GLD16(Ag + (size_t)(m0 + srow) * Kg + (kk) + scol, &Ab[buf][tid * 8]);    \
    GLD16(Ag + (size_t)(m0 + 64 + srow) * Kg + (kk) + scol,                   \
          &Ab[buf][4096 + tid * 8]); } while (0)
#define SB8a(buf, kk) do {                                                    \
    GLD16(Wg + (size_t)(n0 + srow) * Kg + (kk) + scol, &Bb[buf][tid * 8]);    \
    GLD16(Wg + (size_t)(n0 + 64 + srow) * Kg + (kk) + scol,                   \
          &Bb[buf][4096 + tid * 8]); } while (0)
#define SB8b(buf, kk) do {                                                    \
    GLD16(Wg + (size_t)(n0 + 128 + srow) * Kg + (kk) + scol,                  \
          &Bb[buf][8192 + tid * 8]);                                          \
    GLD16(Wg + (size_t)(n0 + 192 + srow) * Kg + (kk) + scol,                  \
          &Bb[buf][12288 + tid * 8]); } while (0)
#define LDFR(rbuf, SW) do { _Pragma("unroll")                                 \
    for (int q_ = 0; q_ < 4; q_++) {                                          \
        af[q_] = *(const short8*)&Ab[rbuf][(wr * 64 + q_ * 16 + lc) * 64 + (SW)];\
        bf[q_] = *(const short8*)&Bb[rbuf][(wc * 64 + q_ * 16 + lc) * 64 + (SW)];\
    } } while (0)
#define MFMA16 do { _Pragma("unroll")                                         \
    for (int mq = 0; mq < 4; mq++) { _Pragma("unroll")                        \
    for (int nq = 0; nq < 4; nq++)                                            \
        acc[mq][nq] = __builtin_amdgcn_mfma_f32_16x16x32_bf16(                \
            af[mq], bf[nq], acc[mq][nq], 0, 0, 0); } } while (0)

#define GEMM8_LOOP                                                            \
    const int NT = Kg >> 6;                                                   \
    SA8(0, 0); SB8a(0, 0); SB8b(0, 0);                                        \
    if (NT > 1) { SA8(1, 64); SB8a(1, 64); SB8b(1, 64); }                     \
    if (NT > 1) asm volatile("s_waitcnt vmcnt(6)" ::: "memory");              \
    else        asm volatile("s_waitcnt vmcnt(0)" ::: "memory");              \
    __builtin_amdgcn_s_barrier();                                             \
    int rb_ = 0, wb_ = 2;                                                     \
    for (int t = 0; t < NT; ++t) {                                            \
        const bool s_ = (t + 2 < NT);                                         \
        const int k2_ = (t + 2) << 6;                                         \
        LDFR(rb_, sw0);                                                       \
        if (s_) { SA8(wb_, k2_); SB8a(wb_, k2_); }                            \
        __builtin_amdgcn_s_barrier();                                         \
        asm volatile("s_waitcnt lgkmcnt(0)" ::: "memory");                    \
        __builtin_amdgcn_s_setprio(1);                                        \
        MFMA16;                                                               \
        __builtin_amdgcn_s_setprio(0);                                        \
        __builtin_amdgcn_s_barrier();                                         \
        LDFR(rb_, sw1);                                                       \
        if (s_) SB8b(wb_, k2_);                                               \
        __builtin_amdgcn_s_barrier();                                         \
        asm volatile("s_waitcnt lgkmcnt(0)" ::: "memory");                    \
        __builtin_amdgcn_s_setprio(1);                                        \
        MFMA16;                                                               \
        __builtin_amdgcn_s_setprio(0);                                        \
        if (s_) asm volatile("s_waitcnt vmcnt(6)" ::: "memory");              \
        else    asm volatile("s_waitcnt vmcnt(0)" ::: "memory");              \
        __builtin_amdgcn_s_barrier();                                         \
        rb_ = (rb_ == 2) ? 0 : rb_ + 1;                                      \
        wb_ = (wb_ == 2) ? 0 : wb_ + 1;                                      \
    }                                                                         \
    const int cb0 = n0 + wc * 64 + lc;                                        \
    const int rb0 = m0 + wr * 64 + quad * 4;

// Generic: C = A @ W^T + bias (+resid EPI=1, relu EPI=2). All bf16.
template<int EPI>
__global__ __launch_bounds__(512, 2) void gemm8(
    const u16* __restrict__ A, const u16* __restrict__ W,
    const u16* __restrict__ bias, const u16* __restrict__ resid,
    u16* __restrict__ C, int N, int K)
{
    GEMM8_PRE(A, W, K)
    GEMM8_LOOP
#pragma unroll
    for (int mq = 0; mq < 4; mq++) {
#pragma unroll
        for (int nq = 0; nq < 4; nq++) {
            const int cN = cb0 + nq * 16;
            const float bv = bf2f(bias[cN]);
#pragma unroll
            for (int i = 0; i < 4; i++) {
                const int rM = rb0 + mq * 16 + i;
                float v = acc[mq][nq][i] + bv;
                if (EPI == 1) v += bf2f(resid[(size_t)rM * N + cN]);
                if (EPI == 2) v = fmaxf(v, 0.0f);
                C[(size_t)rM * N + cN] = f2bf(v);
            }
        }
    }
}

// ---------------------------------------------------------------------------
// gemm256 v2.1: 256x256 tile, BK=64, 512 threads = 8 waves (2M x 4N),
// per-wave 128x64. Double-buffered, K-HALF staged, 4 phases/tile (as v2),
// with the ROUND-5 swizzle restored (round-6's (row>>2) variant caused 6.29M
// bank conflicts; (row>>1) alternates chunks between rows r and r+2 which
// share a 128B bank span -> measured 0 conflicts).
//   staging: LDS linear dest, global col chunk ^= (row>>1)&3
//            (row = tid>>2  =>  s_c = ((tid&3) ^ ((tid>>3)&3)) << 3)
//   read:    frag rows = base + lc (+16j; bits>=4 don't affect (row>>1)&3)
//            =>  fsw = (quad ^ ((lc>>1)&3)) << 3
// Schedule per tile (vmcnt ledger verified, >=6 loads in flight steady-state):
//   ph1: {LDB kk0 + LDA kk0 mh0; stage next B-kk0} bar lgkm MFMA16 bar
//   ph2: {LDA kk0 mh1 (B reused); stage next A-kk1} bar lgkm MFMA16 vmcnt(6) bar
//   ph3: {LDB kk1 + LDA kk1 mh0; stage next B-kk1} bar lgkm MFMA16 bar
//   ph4: {LDA kk1 mh1; stage t+2 A-kk0 into consumed kk0 slot} bar lgkm
//        MFMA16 vmcnt(6|4|0) bar
// ---------------------------------------------------------------------------
#define GEMM256_PRE(Ag_, Wg_, Kg_)                                            \
    __shared__ __align__(16) u16 Ab[2][2][8192];                              \
    __shared__ __align__(16) u16 Bb[2][2][8192];                              \
    const u16* Ag = (Ag_); const u16* Wg = (Wg_); const int Kg = (Kg_);       \
    const int tid  = threadIdx.x;                                             \
    const int lane = tid & 63;                                                \
    const int lc   = lane & 15;                                               \
    const int quad = lane >> 4;                                               \
    const int w    = tid >> 6;                                                \
    const int wr   = w >> 2;                                                  \
    const int wc   = w & 3;                                                   \
    const int m0 = blockIdx.x * 256;                                          \
    const int n0 = blockIdx.y * 256;                                          \
    const int s_r = tid >> 2;                                                 \
    const int s_c = (((tid & 3) ^ ((tid >> 3) & 3)) << 3);                    \
    const int fsw = ((quad ^ ((lc >> 1) & 3)) << 3);                          \
    const int arow = wr * 128 + lc;                                           \
    const int brow = wc * 64 + lc;                                            \
    f32x4 acc[8][4] = {};                                                     \
    short8 af[4], bf[4];

#define SAH(buf, kk, tt) do {                                                 \
    GLD16(Ag + (size_t)(m0 + s_r) * Kg + (tt) * 64 + (kk) * 32 + s_c,         \
          &Ab[buf][kk][tid * 8]);                                             \
    GLD16(Ag + (size_t)(m0 + 128 + s_r) * Kg + (tt) * 64 + (kk) * 32 + s_c,   \
          &Ab[buf][kk][4096 + tid * 8]); } while (0)
#define SBH(buf, kk, tt) do {                                                 \
    GLD16(Wg + (size_t)(n0 + s_r) * Kg + (tt) * 64 + (kk) * 32 + s_c,         \
          &Bb[buf][kk][tid * 8]);                                             \
    GLD16(Wg + (size_t)(n0 + 128 + s_r) * Kg + (tt) * 64 + (kk) * 32 + s_c,   \
          &Bb[buf][kk][4096 + tid * 8]); } while (0)
#define LDA2(buf, kk, MH) do { _Pragma("unroll")                              \
    for (int q_ = 0; q_ < 4; q_++)                                            \
        af[q_] = *(const short8*)                                             \
            &Ab[buf][kk][(arow + ((MH) * 4 + q_) * 16) * 32 + fsw]; } while (0)
#define LDB2(buf, kk) do { _Pragma("unroll")                                  \
    for (int q_ = 0; q_ < 4; q_++)                                            \
        bf[q_] = *(const short8*)                                             \
            &Bb[buf][kk][(brow + q_ * 16) * 32 + fsw]; } while (0)
#define MF256(MH) do { _Pragma("unroll")                                      \
    for (int mq = 0; mq < 4; mq++) { _Pragma("unroll")                        \
    for (int nq = 0; nq < 4; nq++)                                            \
        acc[(MH) * 4 + mq][nq] = __builtin_amdgcn_mfma_f32_16x16x32_bf16(     \
            af[mq], bf[nq], acc[(MH) * 4 + mq][nq], 0, 0, 0); } } while (0)

#define GEMM256_LOOP                                                          \
    const int NT = Kg >> 6;                                                   \
    SAH(0, 0, 0); SBH(0, 0, 0); SAH(0, 1, 0); SBH(0, 1, 0);                   \
    if (NT > 1) SAH(1, 0, 1);                                                 \
    if (NT > 1) asm volatile("s_waitcnt vmcnt(2)" ::: "memory");              \
    else        asm volatile("s_waitcnt vmcnt(0)" ::: "memory");              \
    __builtin_amdgcn_s_barrier();                                             \
    for (int t = 0; t < NT; ++t) {                                            \
        const int c_ = t & 1, nx_ = c_ ^ 1;                                   \
        const bool s1_ = (t + 1 < NT), s2_ = (t + 2 < NT);                    \
        /* ph1: kk0 x mh0 */                                                  \
        LDB2(c_, 0); LDA2(c_, 0, 0);                                          \
        if (s1_) SBH(nx_, 0, t + 1);                                          \
        __builtin_amdgcn_s_barrier();                                         \
        asm volatile("s_waitcnt lgkmcnt(0)" ::: "memory");                    \
        __builtin_amdgcn_s_setprio(1);                                        \
        MF256(0);                                                             \
        __builtin_amdgcn_s_setprio(0);                                        \
        __builtin_amdgcn_s_barrier();                                         \
        /* ph2: kk0 x mh1 (B frags reused) */                                 \
        LDA2(c_, 0, 1);                                                       \
        if (s1_) SAH(nx_, 1, t + 1);                                          \
        __builtin_amdgcn_s_barrier();                                         \
        asm volatile("s_waitcnt lgkmcnt(0)" ::: "memory");                    \
        __builtin_amdgcn_s_setprio(1);                                        \
        MF256(1);                                                             \
        __builtin_amdgcn_s_setprio(0);                                        \
        if (s1_) asm volatile("s_waitcnt vmcnt(6)" ::: "memory");             \
        else     asm volatile("s_waitcnt vmcnt(0)" ::: "memory");             \
        __builtin_amdgcn_s_barrier();                                         \
        /* ph3: kk1 x mh0 */                                                  \
        LDB2(c_, 1); LDA2(c_, 1, 0);                                          \
        if (s1_) SBH(nx_, 1, t + 1);                                          \
        __builtin_amdgcn_s_barrier();                                         \
        asm volatile("s_waitcnt lgkmcnt(0)" ::: "memory");                    \
        __builtin_amdgcn_s_setprio(1);                                        \
        MF256(0);                                                             \
        __builtin_amdgcn_s_setprio(0);                                        \
        __builtin_amdgcn_s_barrier();                                         \
        /* ph4: kk1 x mh1; stage t+2's A-kk0 into consumed kk0 slot */        \
        LDA2(c_, 1, 1);                                                       \
        if (s2_) SAH(c_, 0, t + 2);                                           \
        __builtin_amdgcn_s_barrier();                                         \
        asm volatile("s_waitcnt lgkmcnt(0)" ::: "memory");                    \
        __builtin_amdgcn_s_setprio(1);                                        \
        MF256(1);                                                             \
        __builtin_amdgcn_s_setprio(0);                                        \
        if (s2_)      asm volatile("s_waitcnt vmcnt(6)" ::: "memory");        \
        else if (s1_) asm volatile("s_waitcnt vmcnt(4)" ::: "memory");        \
        else          asm volatile("s_waitcnt vmcnt(0)" ::: "memory");        \
        __builtin_amdgcn_s_barrier();                                         \
    }                                                                         \
    const int cb0 = n0 + wc * 64 + lc;                                        \
    const int rb0 = m0 + wr * 128 + quad * 4;

// Generic 256-tile: C = A @ W^T + bias (+resid EPI=1, relu EPI=2). All bf16.
template<int EPI>
__global__ __launch_bounds__(512, 2) void gemm256(
    const u16* __restrict__ A, const u16* __restrict__ W,
    const u16* __restrict__ bias, const u16* __restrict__ resid,
    u16* __restrict__ C, int N, int K)
{
    GEMM256_PRE(A, W, K)
    GEMM256_LOOP
#pragma unroll
    for (int mq = 0; mq < 8; mq++) {
#pragma unroll
        for (int nq = 0; nq < 4; nq++) {
            const int cN = cb0 + nq * 16;
            const float bv = bf2f(bias[cN]);
#pragma unroll
            for (int i = 0; i < 4; i++) {
                const int rM = rb0 + mq * 16 + i;
                float v = acc[mq][nq][i] + bv;
                if (EPI == 1) v += bf2f(resid[(size_t)rM * N + cN]);
                if (EPI == 2) v = fmaxf(v, 0.0f);
                C[(size_t)rM * N + cN] = f2bf(v);
            }
        }
    }
}

// QKV on the gemm256 core (tier A): N=3072, K=1024. n0 block-uniform branch.
__global__ __launch_bounds__(512, 2) void gemm256_qkv(
    const u16* __restrict__ A, const u16* __restrict__ W,
    const u16* __restrict__ bias,
    u16* __restrict__ Qo, u16* __restrict__ Ko, u16* __restrict__ Vt)
{
    GEMM256_PRE(A, W, 1024)
    GEMM256_LOOP
    if (n0 < 1024) {
#pragma unroll
        for (int mq = 0; mq < 8; mq++)
#pragma unroll
            for (int nq = 0; nq < 4; nq++) {
                const int c = cb0 + nq * 16;
                const float bv = bf2f(bias[c]);
#pragma unroll
                for (int i = 0; i < 4; i++) {
                    const int r = rb0 + mq * 16 + i;
                    Qo[(size_t)r * 1024 + c] =
                        f2bf((acc[mq][nq][i] + bv) * QSCL);
                }
            }
    } else if (n0 < 2048) {
#pragma unroll
        for (int mq = 0; mq < 8; mq++)
#pragma unroll
            for (int nq = 0; nq < 4; nq++) {
                const int c = cb0 + nq * 16;
                const float bv = bf2f(bias[c]);
#pragma unroll
                for (int i = 0; i < 4; i++) {
                    const int r = rb0 + mq * 16 + i;
                    Ko[(size_t)r * 1024 + (c - 1024)] =
                        f2bf(acc[mq][nq][i] + bv);
                }
            }
    } else {
#pragma unroll
        for (int mq = 0; mq < 8; mq++)
#pragma unroll
            for (int nq = 0; nq < 4; nq++) {
                const int c = cb0 + nq * 16;
                const float bv = bf2f(bias[c]);
                const int cv = c - 2048;
                const int hh = cv >> 6, d = cv & 63;
                const int rbase = rb0 + mq * 16;
                const int bl = rbase >> 10, tt = rbase & 1023;
                short4v pk;
#pragma unroll
                for (int i = 0; i < 4; i++)
                    pk[i] = (short)f2bf(acc[mq][nq][i] + bv);
                *(short4v*)&Vt[((size_t)(bl * 16 + hh) * 64 + d) * 1024 + tt] = pk;
            }
    }
}

// ---------------------------------------------------------------------------
// Flash attention v4: Q pre-scaled by log2e so softmax is exp2-native.
// VALU cuts vs v3: block-uniform causal branch; row-sum via MFMA against a
// constant ones-column B fragment (l kept in lc==0 lanes, broadcast at end);
// P->bf16 via v_cvt_pk_bf16_f32 pairs; O-rescale skipped when no new max
// (wave-uniform vote). Paired q-tiles (qt, 7-qt), dbuf K/V. Grid (4, nbh).
// ---------------------------------------------------------------------------
__global__ __launch_bounds__(256, 2) void attn_kernel(
    u16* __restrict__ QO, const u16* __restrict__ Ko,
    const u16* __restrict__ Vt, const float* __restrict__ kb, int b0)
{
    __shared__ __align__(16) u16 Qs[2 * 128 * 32];   // [kcd][qrow][32]
    __shared__ __align__(16) u16 Ks[2][2 * 64 * 32]; // dbuf [kcd][key][32]
    __shared__ __align__(16) u16 Vs[2][2 * 64 * 32]; // dbuf [kck][d][32]
    __shared__ __align__(16) u16 Ps[4][32 * 72];
    __shared__ float kba[1024];

    const int tid  = threadIdx.x;
    const int lane = tid & 63;
    const int w    = tid >> 6;
    const int lc   = lane & 15;
    const int quad = lane >> 4;
    const int bl = blockIdx.y >> 4;
    const int h  = blockIdx.y & 15;
    const int b  = b0 + bl;

    // constant B fragment: B[k][n] = (n==0) ? 1 : 0  ->  D[q][0] = sum_k P[q][k]
    short8 bsum;
    {
        const short ov = (lc == 0) ? (short)0x3F80 : (short)0;
#pragma unroll
        for (int j = 0; j < 8; j++) bsum[j] = ov;
    }

    // preload padding-bias column for this sequence
    *(f32x4*)&kba[tid * 4] = *(const f32x4*)&kb[b * 1024 + tid * 4];

    for (int p = 0; p < 2; p++) {
        const int qt = p ? 7 - (int)blockIdx.x : (int)blockIdx.x;

        // stage Q tile [kcd][128][32]
#pragma unroll
        for (int it = 0; it < 4; it++) {
            const int kcd = it >> 1, half = it & 1;
            const int r = half * 64 + (tid >> 2);
            const int c = kcd * 32 + (tid & 3) * 8;
            GLD16(&QO[((size_t)(b * 1024 + qt * 128 + r)) * 1024 + h * 64 + c],
                  &Qs[kcd * 4096 + half * 2048 + tid * 8]);
        }
        // stage kt=0 into buffer 0
        {
            const int rr = tid >> 2;
#pragma unroll
            for (int it = 0; it < 2; it++) {
                const int cc = it * 32 + (tid & 3) * 8;
                GLD16(&Ko[((size_t)(bl * 1024 + rr)) * 1024 + h * 64 + cc],
                      &Ks[0][it * 2048 + tid * 8]);
                GLD16(&Vt[((size_t)(bl * 16 + h) * 64 + rr) * 1024 + cc],
                      &Vs[0][it * 2048 + tid * 8]);
            }
        }
        __syncthreads();   // Q + K0/V0 (+ kba on p=0) ready

        short8 aq[2][2];
#pragma unroll
        for (int mt = 0; mt < 2; mt++)
#pragma unroll
            for (int kc = 0; kc < 2; kc++)
                aq[mt][kc] = *(const short8*)
                    &Qs[kc * 4096 + (w * 32 + mt * 16 + lc) * 32 + quad * 8];

        f32x4 o[2][4] = {};
        float m_i[2][4], l_i[2][4];
#pragma unroll
        for (int mt = 0; mt < 2; mt++)
#pragma unroll
            for (int i = 0; i < 4; i++) { m_i[mt][i] = -1e30f; l_i[mt][i] = 0.0f; }

        const int ktmax = 2 * qt + 2;
        for (int kt = 0; kt < ktmax; kt++) {
            const int cur = kt & 1;
            // prefetch kt+1 (overlaps with compute below; drained at barrier)
            if (kt + 1 < ktmax) {
                const int nxt = cur ^ 1;
                const int rr = tid >> 2;
#pragma unroll
                for (int it = 0; it < 2; it++) {
                    const int cc = it * 32 + (tid & 3) * 8;
                    GLD16(&Ko[((size_t)(bl * 1024 + (kt + 1) * 64 + rr)) * 1024 + h * 64 + cc],
                          &Ks[nxt][it * 2048 + tid * 8]);
                    GLD16(&Vt[((size_t)(bl * 16 + h) * 64 + rr) * 1024 + (kt + 1) * 64 + cc],
                          &Vs[nxt][it * 2048 + tid * 8]);
                }
            }

            // S = Q K^T  (already in log2 domain via Q pre-scale)
            short8 bk[4][2];
#pragma unroll
            for (int nt = 0; nt < 4; nt++)
#pragma unroll
                for (int kc = 0; kc < 2; kc++)
                    bk[nt][kc] = *(const short8*)
                        &Ks[cur][kc * 2048 + (nt * 16 + lc) * 32 + quad * 8];

            f32x4 s[2][4];
#pragma unroll
            for (int mt = 0; mt < 2; mt++)
#pragma unroll
                for (int nt = 0; nt < 4; nt++) {
                    f32x4 z = {};
#pragma unroll
                    for (int kc = 0; kc < 2; kc++)
                        z = __builtin_amdgcn_mfma_f32_16x16x32_bf16(
                            aq[mt][kc], bk[nt][kc], z, 0, 0, 0);
                    s[mt][nt] = z;
                }

            // padding bias (always) + causal mask (diagonal tiles only)
#pragma unroll
            for (int mt = 0; mt < 2; mt++)
#pragma unroll
                for (int nt = 0; nt < 4; nt++) {
                    const float kbv = kba[kt * 64 + nt * 16 + lc];
#pragma unroll
                    for (int i = 0; i < 4; i++) s[mt][nt][i] += kbv;
                }
            if (kt >= 2 * qt) {   // block-uniform branch
#pragma unroll
                for (int mt = 0; mt < 2; mt++) {
                    const int qg0 = qt * 128 + w * 32 + mt * 16 + quad * 4;
#pragma unroll
                    for (int nt = 0; nt < 4; nt++) {
                        const int kg = kt * 64 + nt * 16 + lc;
#pragma unroll
                        for (int i = 0; i < 4; i++)
                            if (kg > qg0 + i) s[mt][nt][i] = -1e30f;
                    }
                }
            }

            float al[2][4];
#pragma unroll
            for (int mt = 0; mt < 2; mt++) {
                float mnew[4];
#pragma unroll
                for (int i = 0; i < 4; i++) {
                    float rm = fmaxf(fmaxf(s[mt][0][i], s[mt][1][i]),
                                     fmaxf(s[mt][2][i], s[mt][3][i]));
                    rm = fmaxf(rm, __shfl_xor(rm, 1));
                    rm = fmaxf(rm, __shfl_xor(rm, 2));
                    rm = fmaxf(rm, __shfl_xor(rm, 4));
                    rm = fmaxf(rm, __shfl_xor(rm, 8));
                    const float mn = fmaxf(m_i[mt][i], rm);
                    al[mt][i] = exp2f(m_i[mt][i] - mn);
                    m_i[mt][i] = mn;
                    mnew[i] = mn;
                }
#pragma unroll
                for (int nt = 0; nt < 4; nt++)
#pragma unroll
                    for (int i = 0; i < 4; i++)
                        s[mt][nt][i] = exp2f(s[mt][nt][i] - mnew[i]);
                // P -> bf16 via packed cvt (rows quad*4+2j, quad*4+2j+1)
#pragma unroll
                for (int nt = 0; nt < 4; nt++) {
#pragma unroll
                    for (int i2 = 0; i2 < 2; i2++) {
                        unsigned int pk;
                        asm("v_cvt_pk_bf16_f32 %0, %1, %2"
                            : "=v"(pk)
                            : "v"(s[mt][nt][2 * i2]), "v"(s[mt][nt][2 * i2 + 1]));
                        Ps[w][(mt * 16 + quad * 4 + 2 * i2) * 72 + nt * 16 + lc] =
                            (u16)pk;
                        Ps[w][(mt * 16 + quad * 4 + 2 * i2 + 1) * 72 + nt * 16 + lc] =
                            (u16)(pk >> 16);
                    }
                }
            }
            int chg = 0;
#pragma unroll
            for (int mt = 0; mt < 2; mt++)
#pragma unroll
                for (int i = 0; i < 4; i++)
                    chg |= (al[mt][i] != 1.0f) ? 1 : 0;
            const int dor = __any(chg);   // wave-uniform

            // O = O*alpha + P @ V ; l-sum via MFMA against bsum
            short8 ap[2][2], bv2[4][2];
#pragma unroll
            for (int mt = 0; mt < 2; mt++)
#pragma unroll
                for (int kc = 0; kc < 2; kc++)
                    ap[mt][kc] = *(const short8*)
                        &Ps[w][(mt * 16 + lc) * 72 + kc * 32 + quad * 8];
#pragma unroll
            for (int nt = 0; nt < 4; nt++)
#pragma unroll
                for (int kc = 0; kc < 2; kc++)
                    bv2[nt][kc] = *(const short8*)
                        &Vs[cur][kc * 2048 + (nt * 16 + lc) * 32 + quad * 8];

            f32x4 ls[2] = {};
#pragma unroll
            for (int mt = 0; mt < 2; mt++)
#pragma unroll
                for (int kc = 0; kc < 2; kc++)
                    ls[mt] = __builtin_amdgcn_mfma_f32_16x16x32_bf16(
                        ap[mt][kc], bsum, ls[mt], 0, 0, 0);

#pragma unroll
            for (int mt = 0; mt < 2; mt++)
#pragma unroll
                for (int nt = 0; nt < 4; nt++) {
                    f32x4 oo = o[mt][nt];
                    if (dor) {
#pragma unroll
                        for (int i = 0; i < 4; i++) oo[i] *= al[mt][i];
                    }
#pragma unroll
                    for (int kc = 0; kc < 2; kc++)
                        oo = __builtin_amdgcn_mfma_f32_16x16x32_bf16(
                            ap[mt][kc], bv2[nt][kc], oo, 0, 0, 0);
                    o[mt][nt] = oo;
                }
#pragma unroll
            for (int mt = 0; mt < 2; mt++)
#pragma unroll
                for (int i = 0; i < 4; i++)
                    l_i[mt][i] = l_i[mt][i] * al[mt][i] + ls[mt][i];

            __syncthreads();   // prefetch drained; buffers safe to swap
        }

        // write O in place of Q (exclusive slice); true l lives in lc==0 lanes
#pragma unroll
        for (int mt = 0; mt < 2; mt++)
#pragma unroll
            for (int i = 0; i < 4; i++) {
                const float lv = __shfl(l_i[mt][i], (lane & 48));
                const float inv = lv > 0.0f ? 1.0f / lv : 0.0f;
#pragma unroll
                for (int nt = 0; nt < 4; nt++) {
                    const int r = qt * 128 + w * 32 + mt * 16 + quad * 4 + i;
                    const int d = nt * 16 + lc;
                    QO[((size_t)(b * 1024 + r)) * 1024 + h * 64 + d] =
                        f2bf(o[mt][nt][i] * inv);
                }
            }
    }
}

// ---------------------------------------------------------------------------
// LayerNorm, one block/row, biased variance, eps=1e-12.
// ---------------------------------------------------------------------------
template<int IN16, int OUTSEL>
__global__ __launch_bounds__(256) void ln_kernel(
    const void* __restrict__ yv, const void* __restrict__ w,
    const void* __restrict__ bb, void* __restrict__ o, long o_row0,
    const int* __restrict__ flags)
{
    const int row = blockIdx.x;
    const int tid = threadIdx.x;
    const int inf32 = flags[0];
    float x0, x1, x2, x3;
    if (IN16) {
        const u16* p = (const u16*)yv + (size_t)row * 1024 + tid * 4;
        short4v v = *(const short4v*)p;
        x0 = bf2f((u16)v[0]); x1 = bf2f((u16)v[1]);
        x2 = bf2f((u16)v[2]); x3 = bf2f((u16)v[3]);
    } else {
        const float* p = (const float*)yv + (size_t)row * 1024 + tid * 4;
        f32x4 v = *(const f32x4*)p;
        x0 = v[0]; x1 = v[1]; x2 = v[2]; x3 = v[3];
    }
    float s = x0 + x1 + x2 + x3;
    float q = x0 * x0 + x1 * x1 + x2 * x2 + x3 * x3;
#pragma unroll
    for (int off = 32; off; off >>= 1) {
        s += __shfl_xor(s, off);
        q += __shfl_xor(q, off);
    }
    __shared__ float sm[8];
    const int lane = tid & 63, wv = tid >> 6;
    if (lane == 0) { sm[wv] = s; sm[4 + wv] = q; }
    __syncthreads();
    const float ts = sm[0] + sm[1] + sm[2] + sm[3];
    const float tq = sm[4] + sm[5] + sm[6] + sm[7];
    const float mean = ts * (1.0f / 1024.0f);
    float var = tq * (1.0f / 1024.0f) - mean * mean;
    if (var < 0.0f) var = 0.0f;
    const float rinv = rsqrtf(var + 1e-12f);

    const size_t obase = ((size_t)o_row0 + row) * 1024 + tid * 4;
#pragma unroll
    for (int j = 0; j < 4; j++) {
        const int c = tid * 4 + j;
        float xv = (j == 0) ? x0 : (j == 1) ? x1 : (j == 2) ? x2 : x3;
        float v = ldx(w, c, inf32) * ((xv - mean) * rinv) + ldx(bb, c, inf32);
        if (OUTSEL && inf32) ((float*)o)[obase + j] = v;
        else                 ((u16*)o)[obase + j] = f2bf(v);
    }
}

// ---------------------------------------------------------------------------
extern "C" void kernel_launch(void* const* d_in, const int* in_sizes, int n_in,
                              void* d_out, int out_size, void* d_ws, size_t ws_size,
                              hipStream_t stream)
{
    const void* x     = d_in[0];
    const void* in_w  = d_in[1];
    const void* in_b  = d_in[2];
    const void* out_w = d_in[3];
    const void* out_b = d_in[4];
    const void* fc1_w = d_in[5];
    const void* fc1_b = d_in[6];
    const void* fc2_w = d_in[7];
    const void* fc2_b = d_in[8];
    const void* ln1w  = d_in[9];
    const void* ln1b  = d_in[10];
    const void* ln2w  = d_in[11];
    const void* ln2b  = d_in[12];
    const void* pad   = d_in[13];
    u16* outp = (u16*)d_out;
    char* ws = (char*)d_ws;
    dim3 blk(256);
    dim3 blk8(512);

    const size_t MB = 1024 * 1024;
    const bool bigWS = ws_size >= (105 * MB + 64 * 1024);

    if (bigWS) {
        // Tier A layout:
        //  0-16  xb -> x1        16-22 w1b (dead after qkv) \
        //  22-24 wob (dead after proj)  24-32 f1b (dead after fc1) } -> y2 16-32
        //  32-40 f2b   40-41 biases     41-57 Ko    57-73 Vt
        //  73-89 y1    41-105 h (FF)    105+ flags / kbias
        u16*   xb   = (u16*)(ws + 0);
        u16*   x1   = (u16*)(ws + 0);
        u16*   w1b  = (u16*)(ws + 16 * MB);
        u16*   wob  = (u16*)(ws + 22 * MB);
        u16*   f1b  = (u16*)(ws + 24 * MB);
        u16*   f2b  = (u16*)(ws + 32 * MB);
        u16*   inbb = (u16*)(ws + 40 * MB);
        u16*   outbb= (u16*)(ws + 40 * MB + 8192);
        u16*   f1bb = (u16*)(ws + 40 * MB + 16384);
        u16*   f2bb = (u16*)(ws + 40 * MB + 24576);
        u16*   Ko   = (u16*)(ws + 41 * MB);
        u16*   Vt   = (u16*)(ws + 57 * MB);
        u16*   y1   = (u16*)(ws + 73 * MB);
        u16*   h    = (u16*)(ws + 41 * MB);
        u16*   y2   = (u16*)(ws + 16 * MB);
        int*   flags  = (int*)(ws + 105 * MB);
        int*   flagsA = (int*)(ws + 105 * MB + 32);
        float* kbias  = (float*)(ws + 105 * MB + 64);

        probe_kernel<<<dim3(1), dim3(64), 0, stream>>>(x, pad, flags, flagsA);
        mask_to_bias<<<dim3(32), blk, 0, stream>>>(pad, kbias, flags);
        conv4<<<dim3(8192), blk, 0, stream>>>(x, xb, 2097152, flags);
        conv4<<<dim3(3072), blk, 0, stream>>>(in_w, w1b, 786432, flags);
        conv4<<<dim3(1024), blk, 0, stream>>>(out_w, wob, 262144, flags);
        conv4<<<dim3(4096), blk, 0, stream>>>(fc1_w, f1b, 1048576, flags);
        conv4<<<dim3(4096), blk, 0, stream>>>(fc2_w, f2b, 1048576, flags);
        conv4<<<dim3(3), blk, 0, stream>>>(in_b, inbb, 768, flags);
        conv4<<<dim3(1), blk, 0, stream>>>(out_b, outbb, 256, flags);
        conv4<<<dim3(4), blk, 0, stream>>>(fc1_b, f1bb, 1024, flags);
        conv4<<<dim3(1), blk, 0, stream>>>(fc2_b, f2bb, 256, flags);

        // qkv on the gemm256 core: [8192,3072] K=1024
        gemm256_qkv<<<dim3(32, 12), blk8, 0, stream>>>(
            xb, w1b, inbb, outp, Ko, Vt);
        attn_kernel<<<dim3(4, 128), blk, 0, stream>>>(outp, Ko, Vt, kbias, 0);
        // out-proj: y1 = attn @ wob^T + outbb + xb   [8192,1024] K=1024
        gemm8<1><<<dim3(64, 4), blk8, 0, stream>>>(
            outp, wob, outbb, xb, y1, 1024, 1024);
        ln_kernel<1, 0><<<dim3(8192), blk, 0, stream>>>(y1, ln1w, ln1b, x1, 0, flags);
        // fc1: h = relu(x1 @ f1b^T + f1bb)   [8192,4096] K=1024
        gemm256<2><<<dim3(32, 16), blk8, 0, stream>>>(
            x1, f1b, f1bb, nullptr, h, 4096, 1024);
        // fc2: y2 = h @ f2b^T + f2bb + x1    [8192,1024] K=4096
        gemm8<1><<<dim3(64, 4), blk8, 0, stream>>>(
            h, f2b, f2bb, x1, y2, 1024, 4096);
        ln_kernel<1, 1><<<dim3(8192), blk, 0, stream>>>(y2, ln2w, ln2b, d_out, 0, flags);
    } else {
        // Tier C: quartered, 12.6 MB workspace
        u16*   Ko    = (u16*)(ws + 0);
        u16*   Vt    = (u16*)(ws + 4 * MB);
        u16*   y1h   = (u16*)(ws + 0);
        float* acc   = (float*)(ws + 0);
        u16*   hc    = (u16*)(ws + 8 * MB);
        int*   flags  = (int*)(ws + 12 * MB);
        int*   flagsA = (int*)(ws + 12 * MB + 32);
        float* kbias  = (float*)(ws + 12 * MB + 64);

        probe_kernel<<<dim3(1), dim3(64), 0, stream>>>(x, pad, flags, flagsA);
        mask_to_bias<<<dim3(32), blk, 0, stream>>>(pad, kbias, flags);

        for (int q = 0; q < 4; q++) {
            const long r0 = (long)q * 2048;
            gemm_qkv<<<dim3(16, 24), blk, 0, stream>>>(
                x, r0, in_w, in_b, outp, Ko, Vt, flags);
            attn_kernel<<<dim3(4, 32), blk, 0, stream>>>(
                outp, Ko, Vt, kbias, q * 2);
        }
        for (int hf = 0; hf < 2; hf++) {
            const long r0 = (long)hf * 4096;
            gemm_bt<1><<<dim3(32, 8), blk, 0, stream>>>(
                outp, 0, r0, out_w, 0, out_b, 0, x, 1, r0,
                y1h, 0, 1024, 1024, 1024, flags);
            ln_kernel<1, 0><<<dim3(4096), blk, 0, stream>>>(
                y1h, ln1w, ln1b, outp, r0, flags);
        }
        for (int q = 3; q >= 0; q--) {
            const long r0 = (long)q * 2048;
            for (int c = 0; c < 4; c++) {
                gemm_bt<2><<<dim3(16, 8), blk, 0, stream>>>(
                    outp, 0, r0, fc1_w, (long)c * 1024 * 1024, fc1_b, (long)c * 1024,
                    nullptr, 0, 0, hc, 0, 1024, 1024, 1024, flags);
                gemm_accf32<<<dim3(16, 8), blk, 0, stream>>>(
                    hc, fc2_w, (long)c * 1024, fc2_b, outp, r0,
                    acc, 4096, c == 0, flags);
            }
            ln_kernel<0, 1><<<dim3(2048), blk, 0, stream>>>(
                acc, ln2w, ln2b, d_out, r0, flags);
        }
    }
}

// Round 8
// 512.599 us; speedup vs baseline: 1.0274x; 1.0274x over previous
//
#include <hip/hip_runtime.h>

typedef unsigned short u16;
typedef __attribute__((ext_vector_type(8))) short short8;
typedef __attribute__((ext_vector_type(4))) short short4v;
typedef __attribute__((ext_vector_type(4))) float f32x4;

#define DEV static __device__ __forceinline__

DEV float bf2f(u16 h) {
    union { unsigned int u; float f; } v; v.u = ((unsigned int)h) << 16; return v.f;
}
DEV u16 f2bf(float f) {
    union { float f; unsigned int u; } v; v.f = f;
    unsigned int r = (v.u + 0x7fff + ((v.u >> 16) & 1)) >> 16;
    return (u16)r;
}
DEV float ldx(const void* p, size_t i, int f32) {
    return f32 ? ((const float*)p)[i] : bf2f(((const u16*)p)[i]);
}

// 0.125 (HD^-0.5) * log2(e): Q pre-scaled so attention softmax uses exp2 directly.
#define QSCL 0.18033688011112042f

#define GLD16(g, l) __builtin_amdgcn_global_load_lds( \
    (const __attribute__((address_space(1))) void*)(g), \
    (__attribute__((address_space(3))) void*)(l), 16, 0, 0)

#define STAGE(P, pf32, eoff, dst8) do {                                        \
    if (!(pf32)) { GLD16(((const u16*)(P)) + (eoff), (dst8)); }                \
    else {                                                                     \
        const float* _p = ((const float*)(P)) + (eoff);                        \
        f32x4 _a = *(const f32x4*)_p, _b = *(const f32x4*)(_p + 4);            \
        short8 _s;                                                             \
        _s[0]=(short)f2bf(_a[0]); _s[1]=(short)f2bf(_a[1]);                    \
        _s[2]=(short)f2bf(_a[2]); _s[3]=(short)f2bf(_a[3]);                    \
        _s[4]=(short)f2bf(_b[0]); _s[5]=(short)f2bf(_b[1]);                    \
        _s[6]=(short)f2bf(_b[2]); _s[7]=(short)f2bf(_b[3]);                    \
        *(short8*)(dst8) = _s;                                                 \
    } } while (0)

// ---------------------------------------------------------------------------
// Probe: flags[0]=1 -> inputs fp32; flags[1]=1 -> mask is bool bytes.
// ---------------------------------------------------------------------------
__global__ __launch_bounds__(64) void probe_kernel(
    const void* __restrict__ x, const void* __restrict__ pad,
    int* __restrict__ flags, int* __restrict__ flagsA)
{
    const int lane = threadIdx.x;
    const u16* xu = (const u16*)x;
    const unsigned int e = (xu[lane * 2] >> 7) & 0xFF;
    const int sane = (e >= 0x70 && e <= 0x8F) ? 1 : 0;
    unsigned long long m = __ballot(sane);
    const int f32 = (__popcll(m) < 32) ? 1 : 0;

    const unsigned int* pi = (const unsigned int*)pad;
    int bytes = 0;
#pragma unroll
    for (int j = 0; j < 6; j++) {
        unsigned int v = pi[128 + j * 64 + lane];
        if (v > 1u) bytes = 1;
    }
    m = __ballot(bytes);
    if (lane == 0) {
        flags[0] = f32; flags[1] = (m != 0ULL) ? 1 : 0;
        flagsA[0] = 0;  flagsA[1] = 0;
    }
}

// 16B/thread copy-or-convert (8 bf16 out per thread).
__global__ __launch_bounds__(256) void conv8(
    const void* __restrict__ src, u16* __restrict__ dst, int n8,
    const int* __restrict__ flags)
{
    const int i = blockIdx.x * 256 + threadIdx.x;
    if (i >= n8) return;
    if (flags[0]) {
        const float* p = (const float*)src + (size_t)i * 8;
        f32x4 a = *(const f32x4*)p, b = *(const f32x4*)(p + 4);
        short8 s;
        s[0]=(short)f2bf(a[0]); s[1]=(short)f2bf(a[1]);
        s[2]=(short)f2bf(a[2]); s[3]=(short)f2bf(a[3]);
        s[4]=(short)f2bf(b[0]); s[5]=(short)f2bf(b[1]);
        s[6]=(short)f2bf(b[2]); s[7]=(short)f2bf(b[3]);
        ((short8*)dst)[i] = s;
    } else {
        ((short8*)dst)[i] = ((const short8*)src)[i];
    }
}

__global__ __launch_bounds__(256) void mask_to_bias(
    const void* __restrict__ pad, float* __restrict__ out,
    const int* __restrict__ flags)
{
    const int i = blockIdx.x * 256 + threadIdx.x;
    const int mv = flags[1] ? (int)((const unsigned char*)pad)[i]
                            : ((const int*)pad)[i];
    out[i] = mv ? -1e30f : 0.0f;
}

// ---------------------------------------------------------------------------
// Shared GEMM core: 128x128 tile, BK=32, 256 threads (4 waves, 4x4 mfma each).
// (retained for tier C)
// ---------------------------------------------------------------------------
#define GEMM_CORE(Av, ASEL, a_row0, Wv, w_off, ldw, K)                        \
    __shared__ __align__(16) u16 As[128 * 32];                                \
    __shared__ __align__(16) u16 Bs[128 * 32];                                \
    const int inf32 = flags[0];                                               \
    const int af32  = (ASEL) ? inf32 : 0;                                     \
    const int tid  = threadIdx.x;                                             \
    const int lane = tid & 63;                                                \
    const int wave = tid >> 6;                                                \
    const int lc   = lane & 15;                                               \
    const int quad = lane >> 4;                                               \
    const int m0 = blockIdx.x * 128;                                          \
    const int n0 = blockIdx.y * 128;                                          \
    const int wm = (wave >> 1) * 64;                                          \
    const int wn = (wave & 1) * 64;                                           \
    const int r0 = tid >> 2;                                                  \
    const int ko = (tid & 3) * 8;                                             \
    f32x4 acc[4][4] = {};                                                     \
    for (int k0 = 0; k0 < (K); k0 += 32) {                                    \
        STAGE(Av, af32, ((size_t)(a_row0) + m0 + r0) * (K) + k0 + ko,         \
              &As[tid * 8]);                                                  \
        STAGE(Av, af32, ((size_t)(a_row0) + m0 + r0 + 64) * (K) + k0 + ko,    \
              &As[2048 + tid * 8]);                                           \
        STAGE(Wv, inf32, (size_t)(w_off) + (size_t)(n0 + r0) * (ldw) + k0 + ko,\
              &Bs[tid * 8]);                                                  \
        STAGE(Wv, inf32, (size_t)(w_off) + (size_t)(n0 + r0 + 64) * (ldw) + k0 + ko,\
              &Bs[2048 + tid * 8]);                                           \
        __syncthreads();                                                      \
        short8 afr[4], bfr[4];                                                \
        const int qd = quad * 8;                                              \
        _Pragma("unroll")                                                     \
        for (int mt = 0; mt < 4; mt++)                                        \
            afr[mt] = *(const short8*)&As[(wm + mt * 16 + lc) * 32 + qd];     \
        _Pragma("unroll")                                                     \
        for (int nt = 0; nt < 4; nt++)                                        \
            bfr[nt] = *(const short8*)&Bs[(wn + nt * 16 + lc) * 32 + qd];     \
        _Pragma("unroll")                                                     \
        for (int mt = 0; mt < 4; mt++)                                        \
            _Pragma("unroll")                                                 \
            for (int nt = 0; nt < 4; nt++)                                    \
                acc[mt][nt] = __builtin_amdgcn_mfma_f32_16x16x32_bf16(        \
                    afr[mt], bfr[nt], acc[mt][nt], 0, 0, 0);                  \
        __syncthreads();                                                      \
    }                                                                         \
    const int ce0 = n0 + wn + lc;                                             \
    const int re0 = m0 + wm + quad * 4;

// Generic GEMM: C = A @ W^T + bias.  EPI: 0 bias, 1 +resid, 2 +relu.
template<int EPI>
__global__ __launch_bounds__(256, 2) void gemm_bt(
    const void* __restrict__ A, int a_sel, long a_row0,
    const void* __restrict__ W, long w_off,
    const void* __restrict__ bias, long b_off,
    const void* __restrict__ resid, int r_sel, long r_row0,
    u16* __restrict__ C, long c_row0,
    int N, int K, int ldw, const int* __restrict__ flags)
{
    GEMM_CORE(A, a_sel, a_row0, W, w_off, ldw, K)
    const int rf32 = r_sel ? inf32 : 0;
#pragma unroll
    for (int mt = 0; mt < 4; mt++) {
#pragma unroll
        for (int nt = 0; nt < 4; nt++) {
            const int c = ce0 + nt * 16;
            const float bv = ldx(bias, (size_t)b_off + c, inf32);
#pragma unroll
            for (int i = 0; i < 4; i++) {
                const int r = re0 + mt * 16 + i;
                float v = acc[mt][nt][i] + bv;
                if (EPI == 1)
                    v += ldx(resid, ((size_t)r_row0 + r) * N + c, rf32);
                if (EPI == 2) v = fmaxf(v, 0.0f);
                C[((size_t)c_row0 + r) * N + c] = f2bf(v);
            }
        }
    }
}

// QKV GEMM (tier C): N=3072 split epilogue on the 128x128 core.
__global__ __launch_bounds__(256, 2) void gemm_qkv(
    const void* __restrict__ A, long a_row0,
    const void* __restrict__ W, const void* __restrict__ bias,
    u16* __restrict__ Qo, u16* __restrict__ Ko, u16* __restrict__ Vt,
    const int* __restrict__ flags)
{
    GEMM_CORE(A, 1, a_row0, W, 0, 1024, 1024)
    if (n0 < 1024) {
#pragma unroll
        for (int mt = 0; mt < 4; mt++)
#pragma unroll
            for (int nt = 0; nt < 4; nt++) {
                const int c = ce0 + nt * 16;
                const float bv = ldx(bias, c, inf32);
#pragma unroll
                for (int i = 0; i < 4; i++) {
                    const int r = re0 + mt * 16 + i;
                    Qo[((size_t)a_row0 + r) * 1024 + c] =
                        f2bf((acc[mt][nt][i] + bv) * QSCL);
                }
            }
    } else if (n0 < 2048) {
#pragma unroll
        for (int mt = 0; mt < 4; mt++)
#pragma unroll
            for (int nt = 0; nt < 4; nt++) {
                const int c = ce0 + nt * 16;
                const float bv = ldx(bias, c, inf32);
#pragma unroll
                for (int i = 0; i < 4; i++) {
                    const int r = re0 + mt * 16 + i;
                    Ko[(size_t)r * 1024 + (c - 1024)] = f2bf(acc[mt][nt][i] + bv);
                }
            }
    } else {
#pragma unroll
        for (int mt = 0; mt < 4; mt++)
#pragma unroll
            for (int nt = 0; nt < 4; nt++) {
                const int c = ce0 + nt * 16;
                const float bv = ldx(bias, c, inf32);
                const int cv = c - 2048;
                const int hh = cv >> 6, d = cv & 63;
                const int rb = re0 + mt * 16;
                const int bl = rb >> 10, t = rb & 1023;
                short4v pk;
#pragma unroll
                for (int i = 0; i < 4; i++)
                    pk[i] = (short)f2bf(acc[mt][nt][i] + bv);
                *(short4v*)&Vt[((size_t)(bl * 16 + hh) * 64 + d) * 1024 + t] = pk;
            }
    }
}

// fc2 K-chunk accumulating into fp32 (tier C only)
__global__ __launch_bounds__(256, 2) void gemm_accf32(
    const void* __restrict__ A, const void* __restrict__ W, long w_off,
    const void* __restrict__ bias, const u16* __restrict__ resid, long r_row0,
    float* __restrict__ C, int ldw, int init, const int* __restrict__ flags)
{
    GEMM_CORE(A, 0, 0, W, w_off, ldw, 1024)
#pragma unroll
    for (int mt = 0; mt < 4; mt++) {
#pragma unroll
        for (int nt = 0; nt < 4; nt++) {
            const int c = ce0 + nt * 16;
            const float bv = ldx(bias, c, inf32);
#pragma unroll
            for (int i = 0; i < 4; i++) {
                const int r = re0 + mt * 16 + i;
                float v = acc[mt][nt][i];
                if (init) v += bv + bf2f(resid[((size_t)r_row0 + r) * 1024 + c]);
                else      v += C[(size_t)r * 1024 + c];
                C[(size_t)r * 1024 + c] = v;
            }
        }
    }
}

// ---------------------------------------------------------------------------
// gemm8: 128x256 tile, BK=64, 512 threads = 8 waves (2M x 4N), per-wave 64x64.
// Triple-buffered, vmcnt(6). (out-proj / fc2 / qkv — grids that balance at
// 128-row tiles)
// ---------------------------------------------------------------------------
#define GEMM8_PRE(Ag_, Wg_, Kg_)                                              \
    __shared__ __align__(16) u16 Ab[3][128 * 64];                             \
    __shared__ __align__(16) u16 Bb[3][256 * 64];                             \
    const u16* Ag = (Ag_); const u16* Wg = (Wg_); const int Kg = (Kg_);       \
    const int tid  = threadIdx.x;                                             \
    const int lane = tid & 63;                                                \
    const int lc   = lane & 15;                                               \
    const int quad = lane >> 4;                                               \
    const int w    = tid >> 6;                                                \
    const int wr   = w >> 2;                                                  \
    const int wc   = w & 3;                                                   \
    const int m0 = blockIdx.x * 128;                                          \
    const int n0 = blockIdx.y * 256;                                          \
    const int srow = tid >> 3;                                                \
    const int scol = (((tid & 7) ^ (srow & 7)) << 3);                         \
    const int sw0 = (((quad) ^ (lc & 7)) << 3);                               \
    const int sw1 = sw0 ^ 32;                                                 \
    f32x4 acc[4][4] = {};                                                     \
    short8 af[4], bf[4];

#define SA8(buf, kk) do {                                                     \
    GLD16(Ag + (size_t)(m0 + srow) * Kg + (kk) + scol, &Ab[buf][tid * 8]);    \
    GLD16(Ag + (size_t)(m0 + 64 + srow) * Kg + (kk) + scol,                   \
          &Ab[buf][4096 + tid * 8]); } while (0)
#define SB8a(buf, kk) do {                                                    \
    GLD16(Wg + (size_t)(n0 + srow) * Kg + (kk) + scol, &Bb[buf][tid * 8]);    \
    GLD16(Wg + (size_t)(n0 + 64 + srow) * Kg + (kk) + scol,                   \
          &Bb[buf][4096 + tid * 8]); } while (0)
#define SB8b(buf, kk) do {                                                    \
    GLD16(Wg + (size_t)(n0 + 128 + srow) * Kg + (kk) + scol,                  \
          &Bb[buf][8192 + tid * 8]);                                          \
    GLD16(Wg + (size_t)(n0 + 192 + srow) * Kg + (kk) + scol,                  \
          &Bb[buf][12288 + tid * 8]); } while (0)
#define LDFR(rbuf, SW) do { _Pragma("unroll")                                 \
    for (int q_ = 0; q_ < 4; q_++) {                                          \
        af[q_] = *(const short8*)&Ab[rbuf][(wr * 64 + q_ * 16 + lc) * 64 + (SW)];\
        bf[q_] = *(const short8*)&Bb[rbuf][(wc * 64 + q_ * 16 + lc) * 64 + (SW)];\
    } } while (0)
#define MFMA16 do { _Pragma("unroll")                                         \
    for (int mq = 0; mq < 4; mq++) { _Pragma("unroll")                        \
    for (int nq = 0; nq < 4; nq++)                                            \
        acc[mq][nq] = __builtin_amdgcn_mfma_f32_16x16x32_bf16(                \
            af[mq], bf[nq], acc[mq][nq], 0, 0, 0); } } while (0)

#define GEMM8_LOOP                                                            \
    const int NT = Kg >> 6;                                                   \
    SA8(0, 0); SB8a(0, 0); SB8b(0, 0);                                        \
    if (NT > 1) { SA8(1, 64); SB8a(1, 64); SB8b(1, 64); }                     \
    if (NT > 1) asm volatile("s_waitcnt vmcnt(6)" ::: "memory");              \
    else        asm volatile("s_waitcnt vmcnt(0)" ::: "memory");              \
    __builtin_amdgcn_s_barrier();                                             \
    int rb_ = 0, wb_ = 2;                                                     \
    for (int t = 0; t < NT; ++t) {                                            \
        const bool s_ = (t + 2 < NT);                                         \
        const int k2_ = (t + 2) << 6;                                         \
        LDFR(rb_, sw0);                                                       \
        if (s_) { SA8(wb_, k2_); SB8a(wb_, k2_); }                            \
        __builtin_amdgcn_s_barrier();                                         \
        asm volatile("s_waitcnt lgkmcnt(0)" ::: "memory");                    \
        __builtin_amdgcn_s_setprio(1);                                        \
        MFMA16;                                                               \
        __builtin_amdgcn_s_setprio(0);                                        \
        __builtin_amdgcn_s_barrier();                                         \
        LDFR(rb_, sw1);                                                       \
        if (s_) SB8b(wb_, k2_);                                               \
        __builtin_amdgcn_s_barrier();                                         \
        asm volatile("s_waitcnt lgkmcnt(0)" ::: "memory");                    \
        __builtin_amdgcn_s_setprio(1);                                        \
        MFMA16;                                                               \
        __builtin_amdgcn_s_setprio(0);                                        \
        if (s_) asm volatile("s_waitcnt vmcnt(6)" ::: "memory");              \
        else    asm volatile("s_waitcnt vmcnt(0)" ::: "memory");              \
        __builtin_amdgcn_s_barrier();                                         \
        rb_ = (rb_ == 2) ? 0 : rb_ + 1;                                      \
        wb_ = (wb_ == 2) ? 0 : wb_ + 1;                                      \
    }                                                                         \
    const int cb0 = n0 + wc * 64 + lc;                                        \
    const int rb0 = m0 + wr * 64 + quad * 4;

// Generic: C = A @ W^T + bias (+resid EPI=1, relu EPI=2). All bf16.
template<int EPI>
__global__ __launch_bounds__(512, 2) void gemm8(
    const u16* __restrict__ A, const u16* __restrict__ W,
    const u16* __restrict__ bias, const u16* __restrict__ resid,
    u16* __restrict__ C, int N, int K)
{
    GEMM8_PRE(A, W, K)
    GEMM8_LOOP
#pragma unroll
    for (int mq = 0; mq < 4; mq++) {
#pragma unroll
        for (int nq = 0; nq < 4; nq++) {
            const int cN = cb0 + nq * 16;
            const float bv = bf2f(bias[cN]);
#pragma unroll
            for (int i = 0; i < 4; i++) {
                const int rM = rb0 + mq * 16 + i;
                float v = acc[mq][nq][i] + bv;
                if (EPI == 1) v += bf2f(resid[(size_t)rM * N + cN]);
                if (EPI == 2) v = fmaxf(v, 0.0f);
                C[(size_t)rM * N + cN] = f2bf(v);
            }
        }
    }
}

// QKV on the gemm8 core (tier A): N=3072, K=1024, grid (64,12) = 768 blocks
// = 3 balanced rounds (vs gemm256's 384 blocks = 2 rounds, half-idle 2nd).
// n0 block-uniform branch; 256-col tiles lie inside one Q/K/V segment.
__global__ __launch_bounds__(512, 2) void gemm8_qkv(
    const u16* __restrict__ A, const u16* __restrict__ W,
    const u16* __restrict__ bias,
    u16* __restrict__ Qo, u16* __restrict__ Ko, u16* __restrict__ Vt)
{
    GEMM8_PRE(A, W, 1024)
    GEMM8_LOOP
    if (n0 < 1024) {
#pragma unroll
        for (int mq = 0; mq < 4; mq++)
#pragma unroll
            for (int nq = 0; nq < 4; nq++) {
                const int c = cb0 + nq * 16;
                const float bv = bf2f(bias[c]);
#pragma unroll
                for (int i = 0; i < 4; i++) {
                    const int r = rb0 + mq * 16 + i;
                    Qo[(size_t)r * 1024 + c] =
                        f2bf((acc[mq][nq][i] + bv) * QSCL);
                }
            }
    } else if (n0 < 2048) {
#pragma unroll
        for (int mq = 0; mq < 4; mq++)
#pragma unroll
            for (int nq = 0; nq < 4; nq++) {
                const int c = cb0 + nq * 16;
                const float bv = bf2f(bias[c]);
#pragma unroll
                for (int i = 0; i < 4; i++) {
                    const int r = rb0 + mq * 16 + i;
                    Ko[(size_t)r * 1024 + (c - 1024)] =
                        f2bf(acc[mq][nq][i] + bv);
                }
            }
    } else {
#pragma unroll
        for (int mq = 0; mq < 4; mq++)
#pragma unroll
            for (int nq = 0; nq < 4; nq++) {
                const int c = cb0 + nq * 16;
                const float bv = bf2f(bias[c]);
                const int cv = c - 2048;
                const int hh = cv >> 6, d = cv & 63;
                const int rbase = rb0 + mq * 16;
                const int bl = rbase >> 10, tt = rbase & 1023;
                short4v pk;
#pragma unroll
                for (int i = 0; i < 4; i++)
                    pk[i] = (short)f2bf(acc[mq][nq][i] + bv);
                *(short4v*)&Vt[((size_t)(bl * 16 + hh) * 64 + d) * 1024 + tt] = pk;
            }
    }
}

// ---------------------------------------------------------------------------
// gemm256 v2.1: 256x256 tile, BK=64, 512 threads = 8 waves (2M x 4N),
// per-wave 128x64. Double-buffered, K-HALF staged, 4 phases/tile, round-5
// swizzle (0 conflicts): staging s_c = ((tid&3)^((tid>>3)&3))<<3, read
// fsw = (quad^((lc>>1)&3))<<3. (fc1 only — 512-block balanced grid)
// ---------------------------------------------------------------------------
#define GEMM256_PRE(Ag_, Wg_, Kg_)                                            \
    __shared__ __align__(16) u16 Ab2[2][2][8192];                             \
    __shared__ __align__(16) u16 Bb2[2][2][8192];                             \
    const u16* Ag = (Ag_); const u16* Wg = (Wg_); const int Kg = (Kg_);       \
    const int tid  = threadIdx.x;                                             \
    const int lane = tid & 63;                                                \
    const int lc   = lane & 15;                                               \
    const int quad = lane >> 4;                                               \
    const int w    = tid >> 6;                                                \
    const int wr   = w >> 2;                                                  \
    const int wc   = w & 3;                                                   \
    const int m0 = blockIdx.x * 256;                                          \
    const int n0 = blockIdx.y * 256;                                          \
    const int s_r = tid >> 2;                                                 \
    const int s_c = (((tid & 3) ^ ((tid >> 3) & 3)) << 3);                    \
    const int fsw = ((quad ^ ((lc >> 1) & 3)) << 3);                          \
    const int arow = wr * 128 + lc;                                           \
    const int brow = wc * 64 + lc;                                            \
    f32x4 acc[8][4] = {};                                                     \
    short8 af[4], bf[4];

#define SAH(buf, kk, tt) do {                                                 \
    GLD16(Ag + (size_t)(m0 + s_r) * Kg + (tt) * 64 + (kk) * 32 + s_c,         \
          &Ab2[buf][kk][tid * 8]);                                            \
    GLD16(Ag + (size_t)(m0 + 128 + s_r) * Kg + (tt) * 64 + (kk) * 32 + s_c,   \
          &Ab2[buf][kk][4096 + tid * 8]); } while (0)
#define SBH(buf, kk, tt) do {                                                 \
    GLD16(Wg + (size_t)(n0 + s_r) * Kg + (tt) * 64 + (kk) * 32 + s_c,         \
          &Bb2[buf][kk][tid * 8]);                                            \
    GLD16(Wg + (size_t)(n0 + 128 + s_r) * Kg + (tt) * 64 + (kk) * 32 + s_c,   \
          &Bb2[buf][kk][4096 + tid * 8]); } while (0)
#define LDA2(buf, kk, MH) do { _Pragma("unroll")                              \
    for (int q_ = 0; q_ < 4; q_++)                                            \
        af[q_] = *(const short8*)                                             \
            &Ab2[buf][kk][(arow + ((MH) * 4 + q_) * 16) * 32 + fsw]; } while (0)
#define LDB2(buf, kk) do { _Pragma("unroll")                                  \
    for (int q_ = 0; q_ < 4; q_++)                                            \
        bf[q_] = *(const short8*)                                             \
            &Bb2[buf][kk][(brow + q_ * 16) * 32 + fsw]; } while (0)
#define MF256(MH) do { _Pragma("unroll")                                      \
    for (int mq = 0; mq < 4; mq++) { _Pragma("unroll")                        \
    for (int nq = 0; nq < 4; nq++)                                            \
        acc[(MH) * 4 + mq][nq] = __builtin_amdgcn_mfma_f32_16x16x32_bf16(     \
            af[mq], bf[nq], acc[(MH) * 4 + mq][nq], 0, 0, 0); } } while (0)

#define GEMM256_LOOP                                                          \
    const int NT = Kg >> 6;                                                   \
    SAH(0, 0, 0); SBH(0, 0, 0); SAH(0, 1, 0); SBH(0, 1, 0);                   \
    if (NT > 1) SAH(1, 0, 1);                                                 \
    if (NT > 1) asm volatile("s_waitcnt vmcnt(2)" ::: "memory");              \
    else        asm volatile("s_waitcnt vmcnt(0)" ::: "memory");              \
    __builtin_amdgcn_s_barrier();                                             \
    for (int t = 0; t < NT; ++t) {                                            \
        const int c_ = t & 1, nx_ = c_ ^ 1;                                   \
        const bool s1_ = (t + 1 < NT), s2_ = (t + 2 < NT);                    \
        /* ph1: kk0 x mh0 */                                                  \
        LDB2(c_, 0); LDA2(c_, 0, 0);                                          \
        if (s1_) SBH(nx_, 0, t + 1);                                          \
        __builtin_amdgcn_s_barrier();                                         \
        asm volatile("s_waitcnt lgkmcnt(0)" ::: "memory");                    \
        __builtin_amdgcn_s_setprio(1);                                        \
        MF256(0);                                                             \
        __builtin_amdgcn_s_setprio(0);                                        \
        __builtin_amdgcn_s_barrier();                                         \
        /* ph2: kk0 x mh1 (B frags reused) */                                 \
        LDA2(c_, 0, 1);                                                       \
        if (s1_) SAH(nx_, 1, t + 1);                                          \
        __builtin_amdgcn_s_barrier();                                         \
        asm volatile("s_waitcnt lgkmcnt(0)" ::: "memory");                    \
        __builtin_amdgcn_s_setprio(1);                                        \
        MF256(1);                                                             \
        __builtin_amdgcn_s_setprio(0);                                        \
        if (s1_) asm volatile("s_waitcnt vmcnt(6)" ::: "memory");             \
        else     asm volatile("s_waitcnt vmcnt(0)" ::: "memory");             \
        __builtin_amdgcn_s_barrier();                                         \
        /* ph3: kk1 x mh0 */                                                  \
        LDB2(c_, 1); LDA2(c_, 1, 0);                                          \
        if (s1_) SBH(nx_, 1, t + 1);                                          \
        __builtin_amdgcn_s_barrier();                                         \
        asm volatile("s_waitcnt lgkmcnt(0)" ::: "memory");                    \
        __builtin_amdgcn_s_setprio(1);                                        \
        MF256(0);                                                             \
        __builtin_amdgcn_s_setprio(0);                                        \
        __builtin_amdgcn_s_barrier();                                         \
        /* ph4: kk1 x mh1; stage t+2's A-kk0 into consumed kk0 slot */        \
        LDA2(c_, 1, 1);                                                       \
        if (s2_) SAH(c_, 0, t + 2);                                           \
        __builtin_amdgcn_s_barrier();                                         \
        asm volatile("s_waitcnt lgkmcnt(0)" ::: "memory");                    \
        __builtin_amdgcn_s_setprio(1);                                        \
        MF256(1);                                                             \
        __builtin_amdgcn_s_setprio(0);                                        \
        if (s2_)      asm volatile("s_waitcnt vmcnt(6)" ::: "memory");        \
        else if (s1_) asm volatile("s_waitcnt vmcnt(4)" ::: "memory");        \
        else          asm volatile("s_waitcnt vmcnt(0)" ::: "memory");        \
        __builtin_amdgcn_s_barrier();                                         \
    }                                                                         \
    const int cb0 = n0 + wc * 64 + lc;                                        \
    const int rb0 = m0 + wr * 128 + quad * 4;

// Generic 256-tile: C = A @ W^T + bias (+resid EPI=1, relu EPI=2). All bf16.
template<int EPI>
__global__ __launch_bounds__(512, 2) void gemm256(
    const u16* __restrict__ A, const u16* __restrict__ W,
    const u16* __restrict__ bias, const u16* __restrict__ resid,
    u16* __restrict__ C, int N, int K)
{
    GEMM256_PRE(A, W, K)
    GEMM256_LOOP
#pragma unroll
    for (int mq = 0; mq < 8; mq++) {
#pragma unroll
        for (int nq = 0; nq < 4; nq++) {
            const int cN = cb0 + nq * 16;
            const float bv = bf2f(bias[cN]);
#pragma unroll
            for (int i = 0; i < 4; i++) {
                const int rM = rb0 + mq * 16 + i;
                float v = acc[mq][nq][i] + bv;
                if (EPI == 1) v += bf2f(resid[(size_t)rM * N + cN]);
                if (EPI == 2) v = fmaxf(v, 0.0f);
                C[(size_t)rM * N + cN] = f2bf(v);
            }
        }
    }
}

// ---------------------------------------------------------------------------
// Flash attention v4: Q pre-scaled by log2e so softmax is exp2-native.
// Block-uniform causal branch; row-sum via MFMA against a constant
// ones-column B fragment; P->bf16 via v_cvt_pk_bf16_f32; O-rescale skipped
// when no new max. Paired q-tiles (qt, 7-qt), dbuf K/V. Grid (4, nbh).
// ---------------------------------------------------------------------------
__global__ __launch_bounds__(256, 2) void attn_kernel(
    u16* __restrict__ QO, const u16* __restrict__ Ko,
    const u16* __restrict__ Vt, const float* __restrict__ kb, int b0)
{
    __shared__ __align__(16) u16 Qs[2 * 128 * 32];   // [kcd][qrow][32]
    __shared__ __align__(16) u16 Ks[2][2 * 64 * 32]; // dbuf [kcd][key][32]
    __shared__ __align__(16) u16 Vs[2][2 * 64 * 32]; // dbuf [kck][d][32]
    __shared__ __align__(16) u16 Ps[4][32 * 72];
    __shared__ float kba[1024];

    const int tid  = threadIdx.x;
    const int lane = tid & 63;
    const int w    = tid >> 6;
    const int lc   = lane & 15;
    const int quad = lane >> 4;
    const int bl = blockIdx.y >> 4;
    const int h  = blockIdx.y & 15;
    const int b  = b0 + bl;

    // constant B fragment: B[k][n] = (n==0) ? 1 : 0  ->  D[q][0] = sum_k P[q][k]
    short8 bsum;
    {
        const short ov = (lc == 0) ? (short)0x3F80 : (short)0;
#pragma unroll
        for (int j = 0; j < 8; j++) bsum[j] = ov;
    }

    // preload padding-bias column for this sequence
    *(f32x4*)&kba[tid * 4] = *(const f32x4*)&kb[b * 1024 + tid * 4];

    for (int p = 0; p < 2; p++) {
        const int qt = p ? 7 - (int)blockIdx.x : (int)blockIdx.x;

        // stage Q tile [kcd][128][32]
#pragma unroll
        for (int it = 0; it < 4; it++) {
            const int kcd = it >> 1, half = it & 1;
            const int r = half * 64 + (tid >> 2);
            const int c = kcd * 32 + (tid & 3) * 8;
            GLD16(&QO[((size_t)(b * 1024 + qt * 128 + r)) * 1024 + h * 64 + c],
                  &Qs[kcd * 4096 + half * 2048 + tid * 8]);
        }
        // stage kt=0 into buffer 0
        {
            const int rr = tid >> 2;
#pragma unroll
            for (int it = 0; it < 2; it++) {
                const int cc = it * 32 + (tid & 3) * 8;
                GLD16(&Ko[((size_t)(bl * 1024 + rr)) * 1024 + h * 64 + cc],
                      &Ks[0][it * 2048 + tid * 8]);
                GLD16(&Vt[((size_t)(bl * 16 + h) * 64 + rr) * 1024 + cc],
                      &Vs[0][it * 2048 + tid * 8]);
            }
        }
        __syncthreads();   // Q + K0/V0 (+ kba on p=0) ready

        short8 aq[2][2];
#pragma unroll
        for (int mt = 0; mt < 2; mt++)
#pragma unroll
            for (int kc = 0; kc < 2; kc++)
                aq[mt][kc] = *(const short8*)
                    &Qs[kc * 4096 + (w * 32 + mt * 16 + lc) * 32 + quad * 8];

        f32x4 o[2][4] = {};
        float m_i[2][4], l_i[2][4];
#pragma unroll
        for (int mt = 0; mt < 2; mt++)
#pragma unroll
            for (int i = 0; i < 4; i++) { m_i[mt][i] = -1e30f; l_i[mt][i] = 0.0f; }

        const int ktmax = 2 * qt + 2;
        for (int kt = 0; kt < ktmax; kt++) {
            const int cur = kt & 1;
            // prefetch kt+1 (overlaps with compute below; drained at barrier)
            if (kt + 1 < ktmax) {
                const int nxt = cur ^ 1;
                const int rr = tid >> 2;
#pragma unroll
                for (int it = 0; it < 2; it++) {
                    const int cc = it * 32 + (tid & 3) * 8;
                    GLD16(&Ko[((size_t)(bl * 1024 + (kt + 1) * 64 + rr)) * 1024 + h * 64 + cc],
                          &Ks[nxt][it * 2048 + tid * 8]);
                    GLD16(&Vt[((size_t)(bl * 16 + h) * 64 + rr) * 1024 + (kt + 1) * 64 + cc],
                          &Vs[nxt][it * 2048 + tid * 8]);
                }
            }

            // S = Q K^T  (already in log2 domain via Q pre-scale)
            short8 bk[4][2];
#pragma unroll
            for (int nt = 0; nt < 4; nt++)
#pragma unroll
                for (int kc = 0; kc < 2; kc++)
                    bk[nt][kc] = *(const short8*)
                        &Ks[cur][kc * 2048 + (nt * 16 + lc) * 32 + quad * 8];

            f32x4 s[2][4];
#pragma unroll
            for (int mt = 0; mt < 2; mt++)
#pragma unroll
                for (int nt = 0; nt < 4; nt++) {
                    f32x4 z = {};
#pragma unroll
                    for (int kc = 0; kc < 2; kc++)
                        z = __builtin_amdgcn_mfma_f32_16x16x32_bf16(
                            aq[mt][kc], bk[nt][kc], z, 0, 0, 0);
                    s[mt][nt] = z;
                }

            // padding bias (always) + causal mask (diagonal tiles only)
#pragma unroll
            for (int mt = 0; mt < 2; mt++)
#pragma unroll
                for (int nt = 0; nt < 4; nt++) {
                    const float kbv = kba[kt * 64 + nt * 16 + lc];
#pragma unroll
                    for (int i = 0; i < 4; i++) s[mt][nt][i] += kbv;
                }
            if (kt >= 2 * qt) {   // block-uniform branch
#pragma unroll
                for (int mt = 0; mt < 2; mt++) {
                    const int qg0 = qt * 128 + w * 32 + mt * 16 + quad * 4;
#pragma unroll
                    for (int nt = 0; nt < 4; nt++) {
                        const int kg = kt * 64 + nt * 16 + lc;
#pragma unroll
                        for (int i = 0; i < 4; i++)
                            if (kg > qg0 + i) s[mt][nt][i] = -1e30f;
                    }
                }
            }

            float al[2][4];
#pragma unroll
            for (int mt = 0; mt < 2; mt++) {
                float mnew[4];
#pragma unroll
                for (int i = 0; i < 4; i++) {
                    float rm = fmaxf(fmaxf(s[mt][0][i], s[mt][1][i]),
                                     fmaxf(s[mt][2][i], s[mt][3][i]));
                    rm = fmaxf(rm, __shfl_xor(rm, 1));
                    rm = fmaxf(rm, __shfl_xor(rm, 2));
                    rm = fmaxf(rm, __shfl_xor(rm, 4));
                    rm = fmaxf(rm, __shfl_xor(rm, 8));
                    const float mn = fmaxf(m_i[mt][i], rm);
                    al[mt][i] = exp2f(m_i[mt][i] - mn);
                    m_i[mt][i] = mn;
                    mnew[i] = mn;
                }
#pragma unroll
                for (int nt = 0; nt < 4; nt++)
#pragma unroll
                    for (int i = 0; i < 4; i++)
                        s[mt][nt][i] = exp2f(s[mt][nt][i] - mnew[i]);
                // P -> bf16 via packed cvt (rows quad*4+2j, quad*4+2j+1)
#pragma unroll
                for (int nt = 0; nt < 4; nt++) {
#pragma unroll
                    for (int i2 = 0; i2 < 2; i2++) {
                        unsigned int pk;
                        asm("v_cvt_pk_bf16_f32 %0, %1, %2"
                            : "=v"(pk)
                            : "v"(s[mt][nt][2 * i2]), "v"(s[mt][nt][2 * i2 + 1]));
                        Ps[w][(mt * 16 + quad * 4 + 2 * i2) * 72 + nt * 16 + lc] =
                            (u16)pk;
                        Ps[w][(mt * 16 + quad * 4 + 2 * i2 + 1) * 72 + nt * 16 + lc] =
                            (u16)(pk >> 16);
                    }
                }
            }
            int chg = 0;
#pragma unroll
            for (int mt = 0; mt < 2; mt++)
#pragma unroll
                for (int i = 0; i < 4; i++)
                    chg |= (al[mt][i] != 1.0f) ? 1 : 0;
            const int dor = __any(chg);   // wave-uniform

            // O = O*alpha + P @ V ; l-sum via MFMA against bsum
            short8 ap[2][2], bv2[4][2];
#pragma unroll
            for (int mt = 0; mt < 2; mt++)
#pragma unroll
                for (int kc = 0; kc < 2; kc++)
                    ap[mt][kc] = *(const short8*)
                        &Ps[w][(mt * 16 + lc) * 72 + kc * 32 + quad * 8];
#pragma unroll
            for (int nt = 0; nt < 4; nt++)
#pragma unroll
                for (int kc = 0; kc < 2; kc++)
                    bv2[nt][kc] = *(const short8*)
                        &Vs[cur][kc * 2048 + (nt * 16 + lc) * 32 + quad * 8];

            f32x4 ls[2] = {};
#pragma unroll
            for (int mt = 0; mt < 2; mt++)
#pragma unroll
                for (int kc = 0; kc < 2; kc++)
                    ls[mt] = __builtin_amdgcn_mfma_f32_16x16x32_bf16(
                        ap[mt][kc], bsum, ls[mt], 0, 0, 0);

#pragma unroll
            for (int mt = 0; mt < 2; mt++)
#pragma unroll
                for (int nt = 0; nt < 4; nt++) {
                    f32x4 oo = o[mt][nt];
                    if (dor) {
#pragma unroll
                        for (int i = 0; i < 4; i++) oo[i] *= al[mt][i];
                    }
#pragma unroll
                    for (int kc = 0; kc < 2; kc++)
                        oo = __builtin_amdgcn_mfma_f32_16x16x32_bf16(
                            ap[mt][kc], bv2[nt][kc], oo, 0, 0, 0);
                    o[mt][nt] = oo;
                }
#pragma unroll
            for (int mt = 0; mt < 2; mt++)
#pragma unroll
                for (int i = 0; i < 4; i++)
                    l_i[mt][i] = l_i[mt][i] * al[mt][i] + ls[mt][i];

            __syncthreads();   // prefetch drained; buffers safe to swap
        }

        // write O in place of Q (exclusive slice); true l lives in lc==0 lanes
#pragma unroll
        for (int mt = 0; mt < 2; mt++)
#pragma unroll
            for (int i = 0; i < 4; i++) {
                const float lv = __shfl(l_i[mt][i], (lane & 48));
                const float inv = lv > 0.0f ? 1.0f / lv : 0.0f;
#pragma unroll
                for (int nt = 0; nt < 4; nt++) {
                    const int r = qt * 128 + w * 32 + mt * 16 + quad * 4 + i;
                    const int d = nt * 16 + lc;
                    QO[((size_t)(b * 1024 + r)) * 1024 + h * 64 + d] =
                        f2bf(o[mt][nt][i] * inv);
                }
            }
    }
}

// ---------------------------------------------------------------------------
// LayerNorm, one block/row, biased variance, eps=1e-12.
// ---------------------------------------------------------------------------
template<int IN16, int OUTSEL>
__global__ __launch_bounds__(256) void ln_kernel(
    const void* __restrict__ yv, const void* __restrict__ w,
    const void* __restrict__ bb, void* __restrict__ o, long o_row0,
    const int* __restrict__ flags)
{
    const int row = blockIdx.x;
    const int tid = threadIdx.x;
    const int inf32 = flags[0];
    float x0, x1, x2, x3;
    if (IN16) {
        const u16* p = (const u16*)yv + (size_t)row * 1024 + tid * 4;
        short4v v = *(const short4v*)p;
        x0 = bf2f((u16)v[0]); x1 = bf2f((u16)v[1]);
        x2 = bf2f((u16)v[2]); x3 = bf2f((u16)v[3]);
    } else {
        const float* p = (const float*)yv + (size_t)row * 1024 + tid * 4;
        f32x4 v = *(const f32x4*)p;
        x0 = v[0]; x1 = v[1]; x2 = v[2]; x3 = v[3];
    }
    float s = x0 + x1 + x2 + x3;
    float q = x0 * x0 + x1 * x1 + x2 * x2 + x3 * x3;
#pragma unroll
    for (int off = 32; off; off >>= 1) {
        s += __shfl_xor(s, off);
        q += __shfl_xor(q, off);
    }
    __shared__ float sm[8];
    const int lane = tid & 63, wv = tid >> 6;
    if (lane == 0) { sm[wv] = s; sm[4 + wv] = q; }
    __syncthreads();
    const float ts = sm[0] + sm[1] + sm[2] + sm[3];
    const float tq = sm[4] + sm[5] + sm[6] + sm[7];
    const float mean = ts * (1.0f / 1024.0f);
    float var = tq * (1.0f / 1024.0f) - mean * mean;
    if (var < 0.0f) var = 0.0f;
    const float rinv = rsqrtf(var + 1e-12f);

    const size_t obase = ((size_t)o_row0 + row) * 1024 + tid * 4;
#pragma unroll
    for (int j = 0; j < 4; j++) {
        const int c = tid * 4 + j;
        float xv = (j == 0) ? x0 : (j == 1) ? x1 : (j == 2) ? x2 : x3;
        float v = ldx(w, c, inf32) * ((xv - mean) * rinv) + ldx(bb, c, inf32);
        if (OUTSEL && inf32) ((float*)o)[obase + j] = v;
        else                 ((u16*)o)[obase + j] = f2bf(v);
    }
}

// ---------------------------------------------------------------------------
extern "C" void kernel_launch(void* const* d_in, const int* in_sizes, int n_in,
                              void* d_out, int out_size, void* d_ws, size_t ws_size,
                              hipStream_t stream)
{
    const void* x     = d_in[0];
    const void* in_w  = d_in[1];
    const void* in_b  = d_in[2];
    const void* out_w = d_in[3];
    const void* out_b = d_in[4];
    const void* fc1_w = d_in[5];
    const void* fc1_b = d_in[6];
    const void* fc2_w = d_in[7];
    const void* fc2_b = d_in[8];
    const void* ln1w  = d_in[9];
    const void* ln1b  = d_in[10];
    const void* ln2w  = d_in[11];
    const void* ln2b  = d_in[12];
    const void* pad   = d_in[13];
    u16* outp = (u16*)d_out;
    char* ws = (char*)d_ws;
    dim3 blk(256);
    dim3 blk8(512);

    const size_t MB = 1024 * 1024;
    const bool bigWS = ws_size >= (105 * MB + 64 * 1024);

    if (bigWS) {
        // Tier A layout:
        //  0-16  xb -> x1        16-22 w1b (dead after qkv) \
        //  22-24 wob (dead after proj)  24-32 f1b (dead after fc1) } -> y2 16-32
        //  32-40 f2b   40-41 biases     41-57 Ko    57-73 Vt
        //  73-89 y1    41-105 h (FF)    105+ flags / kbias
        u16*   xb   = (u16*)(ws + 0);
        u16*   x1   = (u16*)(ws + 0);
        u16*   w1b  = (u16*)(ws + 16 * MB);
        u16*   wob  = (u16*)(ws + 22 * MB);
        u16*   f1b  = (u16*)(ws + 24 * MB);
        u16*   f2b  = (u16*)(ws + 32 * MB);
        u16*   inbb = (u16*)(ws + 40 * MB);
        u16*   outbb= (u16*)(ws + 40 * MB + 8192);
        u16*   f1bb = (u16*)(ws + 40 * MB + 16384);
        u16*   f2bb = (u16*)(ws + 40 * MB + 24576);
        u16*   Ko   = (u16*)(ws + 41 * MB);
        u16*   Vt   = (u16*)(ws + 57 * MB);
        u16*   y1   = (u16*)(ws + 73 * MB);
        u16*   h    = (u16*)(ws + 41 * MB);
        u16*   y2   = (u16*)(ws + 16 * MB);
        int*   flags  = (int*)(ws + 105 * MB);
        int*   flagsA = (int*)(ws + 105 * MB + 32);
        float* kbias  = (float*)(ws + 105 * MB + 64);

        probe_kernel<<<dim3(1), dim3(64), 0, stream>>>(x, pad, flags, flagsA);
        mask_to_bias<<<dim3(32), blk, 0, stream>>>(pad, kbias, flags);
        conv8<<<dim3(4096), blk, 0, stream>>>(x, xb, 1048576, flags);
        conv8<<<dim3(1536), blk, 0, stream>>>(in_w, w1b, 393216, flags);
        conv8<<<dim3(512),  blk, 0, stream>>>(out_w, wob, 131072, flags);
        conv8<<<dim3(2048), blk, 0, stream>>>(fc1_w, f1b, 524288, flags);
        conv8<<<dim3(2048), blk, 0, stream>>>(fc2_w, f2b, 524288, flags);
        conv8<<<dim3(2), blk, 0, stream>>>(in_b, inbb, 384, flags);
        conv8<<<dim3(1), blk, 0, stream>>>(out_b, outbb, 128, flags);
        conv8<<<dim3(2), blk, 0, stream>>>(fc1_b, f1bb, 512, flags);
        conv8<<<dim3(1), blk, 0, stream>>>(fc2_b, f2bb, 128, flags);

        // qkv on the gemm8 core: [8192,3072] K=1024, 768 blocks = 3 rounds
        gemm8_qkv<<<dim3(64, 12), blk8, 0, stream>>>(
            xb, w1b, inbb, outp, Ko, Vt);
        attn_kernel<<<dim3(4, 128), blk, 0, stream>>>(outp, Ko, Vt, kbias, 0);
        // out-proj: y1 = attn @ wob^T + outbb + xb   [8192,1024] K=1024
        gemm8<1><<<dim3(64, 4), blk8, 0, stream>>>(
            outp, wob, outbb, xb, y1, 1024, 1024);
        ln_kernel<1, 0><<<dim3(8192), blk, 0, stream>>>(y1, ln1w, ln1b, x1, 0, flags);
        // fc1: h = relu(x1 @ f1b^T + f1bb)   [8192,4096] K=1024
        gemm256<2><<<dim3(32, 16), blk8, 0, stream>>>(
            x1, f1b, f1bb, nullptr, h, 4096, 1024);
        // fc2: y2 = h @ f2b^T + f2bb + x1    [8192,1024] K=4096
        gemm8<1><<<dim3(64, 4), blk8, 0, stream>>>(
            h, f2b, f2bb, x1, y2, 1024, 4096);
        ln_kernel<1, 1><<<dim3(8192), blk, 0, stream>>>(y2, ln2w, ln2b, d_out, 0, flags);
    } else {
        // Tier C: quartered, 12.6 MB workspace
        u16*   Ko    = (u16*)(ws + 0);
        u16*   Vt    = (u16*)(ws + 4 * MB);
        u16*   y1h   = (u16*)(ws + 0);
        float* acc   = (float*)(ws + 0);
        u16*   hc    = (u16*)(ws + 8 * MB);
        int*   flags  = (int*)(ws + 12 * MB);
        int*   flagsA = (int*)(ws + 12 * MB + 32);
        float* kbias  = (float*)(ws + 12 * MB + 64);

        probe_kernel<<<dim3(1), dim3(64), 0, stream>>>(x, pad, flags, flagsA);
        mask_to_bias<<<dim3(32), blk, 0, stream>>>(pad, kbias, flags);

        for (int q = 0; q < 4; q++) {
            const long r0 = (long)q * 2048;
            gemm_qkv<<<dim3(16, 24), blk, 0, stream>>>(
                x, r0, in_w, in_b, outp, Ko, Vt, flags);
            attn_kernel<<<dim3(4, 32), blk, 0, stream>>>(
                outp, Ko, Vt, kbias, q * 2);
        }
        for (int hf = 0; hf < 2; hf++) {
            const long r0 = (long)hf * 4096;
            gemm_bt<1><<<dim3(32, 8), blk, 0, stream>>>(
                outp, 0, r0, out_w, 0, out_b, 0, x, 1, r0,
                y1h, 0, 1024, 1024, 1024, flags);
            ln_kernel<1, 0><<<dim3(4096), blk, 0, stream>>>(
                y1h, ln1w, ln1b, outp, r0, flags);
        }
        for (int q = 3; q >= 0; q--) {
            const long r0 = (long)q * 2048;
            for (int c = 0; c < 4; c++) {
                gemm_bt<2><<<dim3(16, 8), blk, 0, stream>>>(
                    outp, 0, r0, fc1_w, (long)c * 1024 * 1024, fc1_b, (long)c * 1024,
                    nullptr, 0, 0, hc, 0, 1024, 1024, 1024, flags);
                gemm_accf32<<<dim3(16, 8), blk, 0, stream>>>(
                    hc, fc2_w, (long)c * 1024, fc2_b, outp, r0,
                    acc, 4096, c == 0, flags);
            }
            ln_kernel<0, 1><<<dim3(2048), blk, 0, stream>>>(
                acc, ln2w, ln2b, d_out, r0, flags);
        }
    }
}

// Round 9
// 499.934 us; speedup vs baseline: 1.0534x; 1.0253x over previous
//
#include <hip/hip_runtime.h>

typedef unsigned short u16;
typedef __attribute__((ext_vector_type(8))) short short8;
typedef __attribute__((ext_vector_type(4))) short short4v;
typedef __attribute__((ext_vector_type(4))) float f32x4;

#define DEV static __device__ __forceinline__

DEV float bf2f(u16 h) {
    union { unsigned int u; float f; } v; v.u = ((unsigned int)h) << 16; return v.f;
}
DEV u16 f2bf(float f) {
    union { float f; unsigned int u; } v; v.f = f;
    unsigned int r = (v.u + 0x7fff + ((v.u >> 16) & 1)) >> 16;
    return (u16)r;
}
DEV float ldx(const void* p, size_t i, int f32) {
    return f32 ? ((const float*)p)[i] : bf2f(((const u16*)p)[i]);
}

// 0.125 (HD^-0.5) * log2(e): Q pre-scaled so attention softmax uses exp2 directly.
#define QSCL 0.18033688011112042f

#define GLD16(g, l) __builtin_amdgcn_global_load_lds( \
    (const __attribute__((address_space(1))) void*)(g), \
    (__attribute__((address_space(3))) void*)(l), 16, 0, 0)

#define STAGE(P, pf32, eoff, dst8) do {                                        \
    if (!(pf32)) { GLD16(((const u16*)(P)) + (eoff), (dst8)); }                \
    else {                                                                     \
        const float* _p = ((const float*)(P)) + (eoff);                        \
        f32x4 _a = *(const f32x4*)_p, _b = *(const f32x4*)(_p + 4);            \
        short8 _s;                                                             \
        _s[0]=(short)f2bf(_a[0]); _s[1]=(short)f2bf(_a[1]);                    \
        _s[2]=(short)f2bf(_a[2]); _s[3]=(short)f2bf(_a[3]);                    \
        _s[4]=(short)f2bf(_b[0]); _s[5]=(short)f2bf(_b[1]);                    \
        _s[6]=(short)f2bf(_b[2]); _s[7]=(short)f2bf(_b[3]);                    \
        *(short8*)(dst8) = _s;                                                 \
    } } while (0)

// ---------------------------------------------------------------------------
// Probe: flags[0]=1 -> inputs fp32; flags[1]=1 -> mask is bool bytes.
// ---------------------------------------------------------------------------
__global__ __launch_bounds__(64) void probe_kernel(
    const void* __restrict__ x, const void* __restrict__ pad,
    int* __restrict__ flags, int* __restrict__ flagsA)
{
    const int lane = threadIdx.x;
    const u16* xu = (const u16*)x;
    const unsigned int e = (xu[lane * 2] >> 7) & 0xFF;
    const int sane = (e >= 0x70 && e <= 0x8F) ? 1 : 0;
    unsigned long long m = __ballot(sane);
    const int f32 = (__popcll(m) < 32) ? 1 : 0;

    const unsigned int* pi = (const unsigned int*)pad;
    int bytes = 0;
#pragma unroll
    for (int j = 0; j < 6; j++) {
        unsigned int v = pi[128 + j * 64 + lane];
        if (v > 1u) bytes = 1;
    }
    m = __ballot(bytes);
    if (lane == 0) {
        flags[0] = f32; flags[1] = (m != 0ULL) ? 1 : 0;
        flagsA[0] = 0;  flagsA[1] = 0;
    }
}

// One fused conversion kernel for all tier-A buffers (16B/thread).
// Segment map in 8-elem units (fixed problem shape):
//   x[0,1048576) in_w[..1441792) out_w[..1572864) fc1_w[..2097152)
//   fc2_w[..2621440) in_b[..2621824) out_b[..2621952) fc1_b[..2622464)
//   fc2_b[..2622592)
__global__ __launch_bounds__(256) void conv_all(
    const void* __restrict__ x, const void* __restrict__ in_w,
    const void* __restrict__ out_w, const void* __restrict__ fc1_w,
    const void* __restrict__ fc2_w, const void* __restrict__ in_b,
    const void* __restrict__ out_b, const void* __restrict__ fc1_b,
    const void* __restrict__ fc2_b,
    u16* __restrict__ xb, u16* __restrict__ w1b, u16* __restrict__ wob,
    u16* __restrict__ f1b, u16* __restrict__ f2b, u16* __restrict__ inbb,
    u16* __restrict__ outbb, u16* __restrict__ f1bb, u16* __restrict__ f2bb,
    const int* __restrict__ flags)
{
    const size_t i = (size_t)blockIdx.x * 256 + threadIdx.x;
    const void* src; u16* dst; size_t off;
    if      (i < 1048576u) { src = x;     dst = xb;    off = i; }
    else if (i < 1441792u) { src = in_w;  dst = w1b;   off = i - 1048576u; }
    else if (i < 1572864u) { src = out_w; dst = wob;   off = i - 1441792u; }
    else if (i < 2097152u) { src = fc1_w; dst = f1b;   off = i - 1572864u; }
    else if (i < 2621440u) { src = fc2_w; dst = f2b;   off = i - 2097152u; }
    else if (i < 2621824u) { src = in_b;  dst = inbb;  off = i - 2621440u; }
    else if (i < 2621952u) { src = out_b; dst = outbb; off = i - 2621824u; }
    else if (i < 2622464u) { src = fc1_b; dst = f1bb;  off = i - 2621952u; }
    else if (i < 2622592u) { src = fc2_b; dst = f2bb;  off = i - 2622464u; }
    else return;
    if (flags[0]) {
        const float* p = (const float*)src + off * 8;
        f32x4 a = *(const f32x4*)p, b = *(const f32x4*)(p + 4);
        short8 s;
        s[0]=(short)f2bf(a[0]); s[1]=(short)f2bf(a[1]);
        s[2]=(short)f2bf(a[2]); s[3]=(short)f2bf(a[3]);
        s[4]=(short)f2bf(b[0]); s[5]=(short)f2bf(b[1]);
        s[6]=(short)f2bf(b[2]); s[7]=(short)f2bf(b[3]);
        ((short8*)dst)[off] = s;
    } else {
        ((short8*)dst)[off] = ((const short8*)src)[off];
    }
}

__global__ __launch_bounds__(256) void mask_to_bias(
    const void* __restrict__ pad, float* __restrict__ out,
    const int* __restrict__ flags)
{
    const int i = blockIdx.x * 256 + threadIdx.x;
    const int mv = flags[1] ? (int)((const unsigned char*)pad)[i]
                            : ((const int*)pad)[i];
    out[i] = mv ? -1e30f : 0.0f;
}

// ---------------------------------------------------------------------------
// Shared GEMM core: 128x128 tile, BK=32, 256 threads (4 waves, 4x4 mfma each).
// (retained for tier C)
// ---------------------------------------------------------------------------
#define GEMM_CORE(Av, ASEL, a_row0, Wv, w_off, ldw, K)                        \
    __shared__ __align__(16) u16 As[128 * 32];                                \
    __shared__ __align__(16) u16 Bs[128 * 32];                                \
    const int inf32 = flags[0];                                               \
    const int af32  = (ASEL) ? inf32 : 0;                                     \
    const int tid  = threadIdx.x;                                             \
    const int lane = tid & 63;                                                \
    const int wave = tid >> 6;                                                \
    const int lc   = lane & 15;                                               \
    const int quad = lane >> 4;                                               \
    const int m0 = blockIdx.x * 128;                                          \
    const int n0 = blockIdx.y * 128;                                          \
    const int wm = (wave >> 1) * 64;                                          \
    const int wn = (wave & 1) * 64;                                           \
    const int r0 = tid >> 2;                                                  \
    const int ko = (tid & 3) * 8;                                             \
    f32x4 acc[4][4] = {};                                                     \
    for (int k0 = 0; k0 < (K); k0 += 32) {                                    \
        STAGE(Av, af32, ((size_t)(a_row0) + m0 + r0) * (K) + k0 + ko,         \
              &As[tid * 8]);                                                  \
        STAGE(Av, af32, ((size_t)(a_row0) + m0 + r0 + 64) * (K) + k0 + ko,    \
              &As[2048 + tid * 8]);                                           \
        STAGE(Wv, inf32, (size_t)(w_off) + (size_t)(n0 + r0) * (ldw) + k0 + ko,\
              &Bs[tid * 8]);                                                  \
        STAGE(Wv, inf32, (size_t)(w_off) + (size_t)(n0 + r0 + 64) * (ldw) + k0 + ko,\
              &Bs[2048 + tid * 8]);                                           \
        __syncthreads();                                                      \
        short8 afr[4], bfr[4];                                                \
        const int qd = quad * 8;                                              \
        _Pragma("unroll")                                                     \
        for (int mt = 0; mt < 4; mt++)                                        \
            afr[mt] = *(const short8*)&As[(wm + mt * 16 + lc) * 32 + qd];     \
        _Pragma("unroll")                                                     \
        for (int nt = 0; nt < 4; nt++)                                        \
            bfr[nt] = *(const short8*)&Bs[(wn + nt * 16 + lc) * 32 + qd];     \
        _Pragma("unroll")                                                     \
        for (int mt = 0; mt < 4; mt++)                                        \
            _Pragma("unroll")                                                 \
            for (int nt = 0; nt < 4; nt++)                                    \
                acc[mt][nt] = __builtin_amdgcn_mfma_f32_16x16x32_bf16(        \
                    afr[mt], bfr[nt], acc[mt][nt], 0, 0, 0);                  \
        __syncthreads();                                                      \
    }                                                                         \
    const int ce0 = n0 + wn + lc;                                             \
    const int re0 = m0 + wm + quad * 4;

// Generic GEMM: C = A @ W^T + bias.  EPI: 0 bias, 1 +resid, 2 +relu.
template<int EPI>
__global__ __launch_bounds__(256, 2) void gemm_bt(
    const void* __restrict__ A, int a_sel, long a_row0,
    const void* __restrict__ W, long w_off,
    const void* __restrict__ bias, long b_off,
    const void* __restrict__ resid, int r_sel, long r_row0,
    u16* __restrict__ C, long c_row0,
    int N, int K, int ldw, const int* __restrict__ flags)
{
    GEMM_CORE(A, a_sel, a_row0, W, w_off, ldw, K)
    const int rf32 = r_sel ? inf32 : 0;
#pragma unroll
    for (int mt = 0; mt < 4; mt++) {
#pragma unroll
        for (int nt = 0; nt < 4; nt++) {
            const int c = ce0 + nt * 16;
            const float bv = ldx(bias, (size_t)b_off + c, inf32);
#pragma unroll
            for (int i = 0; i < 4; i++) {
                const int r = re0 + mt * 16 + i;
                float v = acc[mt][nt][i] + bv;
                if (EPI == 1)
                    v += ldx(resid, ((size_t)r_row0 + r) * N + c, rf32);
                if (EPI == 2) v = fmaxf(v, 0.0f);
                C[((size_t)c_row0 + r) * N + c] = f2bf(v);
            }
        }
    }
}

// QKV GEMM (tier C): N=3072 split epilogue on the 128x128 core.
__global__ __launch_bounds__(256, 2) void gemm_qkv(
    const void* __restrict__ A, long a_row0,
    const void* __restrict__ W, const void* __restrict__ bias,
    u16* __restrict__ Qo, u16* __restrict__ Ko, u16* __restrict__ Vt,
    const int* __restrict__ flags)
{
    GEMM_CORE(A, 1, a_row0, W, 0, 1024, 1024)
    if (n0 < 1024) {
#pragma unroll
        for (int mt = 0; mt < 4; mt++)
#pragma unroll
            for (int nt = 0; nt < 4; nt++) {
                const int c = ce0 + nt * 16;
                const float bv = ldx(bias, c, inf32);
#pragma unroll
                for (int i = 0; i < 4; i++) {
                    const int r = re0 + mt * 16 + i;
                    Qo[((size_t)a_row0 + r) * 1024 + c] =
                        f2bf((acc[mt][nt][i] + bv) * QSCL);
                }
            }
    } else if (n0 < 2048) {
#pragma unroll
        for (int mt = 0; mt < 4; mt++)
#pragma unroll
            for (int nt = 0; nt < 4; nt++) {
                const int c = ce0 + nt * 16;
                const float bv = ldx(bias, c, inf32);
#pragma unroll
                for (int i = 0; i < 4; i++) {
                    const int r = re0 + mt * 16 + i;
                    Ko[(size_t)r * 1024 + (c - 1024)] = f2bf(acc[mt][nt][i] + bv);
                }
            }
    } else {
#pragma unroll
        for (int mt = 0; mt < 4; mt++)
#pragma unroll
            for (int nt = 0; nt < 4; nt++) {
                const int c = ce0 + nt * 16;
                const float bv = ldx(bias, c, inf32);
                const int cv = c - 2048;
                const int hh = cv >> 6, d = cv & 63;
                const int rb = re0 + mt * 16;
                const int bl = rb >> 10, t = rb & 1023;
                short4v pk;
#pragma unroll
                for (int i = 0; i < 4; i++)
                    pk[i] = (short)f2bf(acc[mt][nt][i] + bv);
                *(short4v*)&Vt[((size_t)(bl * 16 + hh) * 64 + d) * 1024 + t] = pk;
            }
    }
}

// fc2 K-chunk accumulating into fp32 (tier C only)
__global__ __launch_bounds__(256, 2) void gemm_accf32(
    const void* __restrict__ A, const void* __restrict__ W, long w_off,
    const void* __restrict__ bias, const u16* __restrict__ resid, long r_row0,
    float* __restrict__ C, int ldw, int init, const int* __restrict__ flags)
{
    GEMM_CORE(A, 0, 0, W, w_off, ldw, 1024)
#pragma unroll
    for (int mt = 0; mt < 4; mt++) {
#pragma unroll
        for (int nt = 0; nt < 4; nt++) {
            const int c = ce0 + nt * 16;
            const float bv = ldx(bias, c, inf32);
#pragma unroll
            for (int i = 0; i < 4; i++) {
                const int r = re0 + mt * 16 + i;
                float v = acc[mt][nt][i];
                if (init) v += bv + bf2f(resid[((size_t)r_row0 + r) * 1024 + c]);
                else      v += C[(size_t)r * 1024 + c];
                C[(size_t)r * 1024 + c] = v;
            }
        }
    }
}

// ---------------------------------------------------------------------------
// gemm8: 128x256 tile, BK=64, 512 threads = 8 waves (2M x 4N), per-wave 64x64.
// Triple-buffered, vmcnt(6). (out-proj / fc2 / qkv)
// ---------------------------------------------------------------------------
#define GEMM8_PRE(Ag_, Wg_, Kg_)                                              \
    __shared__ __align__(16) u16 Ab[3][128 * 64];                             \
    __shared__ __align__(16) u16 Bb[3][256 * 64];                             \
    const u16* Ag = (Ag_); const u16* Wg = (Wg_); const int Kg = (Kg_);       \
    const int tid  = threadIdx.x;                                             \
    const int lane = tid & 63;                                                \
    const int lc   = lane & 15;                                               \
    const int quad = lane >> 4;                                               \
    const int w    = tid >> 6;                                                \
    const int wr   = w >> 2;                                                  \
    const int wc   = w & 3;                                                   \
    const int m0 = blockIdx.x * 128;                                          \
    const int n0 = blockIdx.y * 256;                                          \
    const int srow = tid >> 3;                                                \
    const int scol = (((tid & 7) ^ (srow & 7)) << 3);                         \
    const int sw0 = (((quad) ^ (lc & 7)) << 3);                               \
    const int sw1 = sw0 ^ 32;                                                 \
    f32x4 acc[4][4] = {};                                                     \
    short8 af[4], bf[4];

#define SA8(buf, kk) do {                                                     \
    GLD16(Ag + (size_t)(m0 + srow) * Kg + (kk) + scol, &Ab[buf][tid * 8]);    \
    GLD16(Ag + (size_t)(m0 + 64 + srow) * Kg + (kk) + scol,                   \
          &Ab[buf][4096 + tid * 8]); } while (0)
#define SB8a(buf, kk) do {                                                    \
    GLD16(Wg + (size_t)(n0 + srow) * Kg + (kk) + scol, &Bb[buf][tid * 8]);    \
    GLD16(Wg + (size_t)(n0 + 64 + srow) * Kg + (kk) + scol,                   \
          &Bb[buf][4096 + tid * 8]); } while (0)
#define SB8b(buf, kk) do {                                                    \
    GLD16(Wg + (size_t)(n0 + 128 + srow) * Kg + (kk) + scol,                  \
          &Bb[buf][8192 + tid * 8]);                                          \
    GLD16(Wg + (size_t)(n0 + 192 + srow) * Kg + (kk) + scol,                  \
          &Bb[buf][12288 + tid * 8]); } while (0)
#define LDFR(rbuf, SW) do { _Pragma("unroll")                                 \
    for (int q_ = 0; q_ < 4; q_++) {                                          \
        af[q_] = *(const short8*)&Ab[rbuf][(wr * 64 + q_ * 16 + lc) * 64 + (SW)];\
        bf[q_] = *(const short8*)&Bb[rbuf][(wc * 64 + q_ * 16 + lc) * 64 + (SW)];\
    } } while (0)
#define MFMA16 do { _Pragma("unroll")                                         \
    for (int mq = 0; mq < 4; mq++) { _Pragma("unroll")                        \
    for (int nq = 0; nq < 4; nq++)                                            \
        acc[mq][nq] = __builtin_amdgcn_mfma_f32_16x16x32_bf16(                \
            af[mq], bf[nq], acc[mq][nq], 0, 0, 0); } } while (0)

#define GEMM8_LOOP                                                            \
    const int NT = Kg >> 6;                                                   \
    SA8(0, 0); SB8a(0, 0); SB8b(0, 0);                                        \
    if (NT > 1) { SA8(1, 64); SB8a(1, 64); SB8b(1, 64); }                     \
    if (NT > 1) asm volatile("s_waitcnt vmcnt(6)" ::: "memory");              \
    else        asm volatile("s_waitcnt vmcnt(0)" ::: "memory");              \
    __builtin_amdgcn_s_barrier();                                             \
    int rb_ = 0, wb_ = 2;                                                     \
    for (int t = 0; t < NT; ++t) {                                            \
        const bool s_ = (t + 2 < NT);                                         \
        const int k2_ = (t + 2) << 6;                                         \
        LDFR(rb_, sw0);                                                       \
        if (s_) { SA8(wb_, k2_); SB8a(wb_, k2_); }                            \
        __builtin_amdgcn_s_barrier();                                         \
        asm volatile("s_waitcnt lgkmcnt(0)" ::: "memory");                    \
        __builtin_amdgcn_s_setprio(1);                                        \
        MFMA16;                                                               \
        __builtin_amdgcn_s_setprio(0);                                        \
        __builtin_amdgcn_s_barrier();                                         \
        LDFR(rb_, sw1);                                                       \
        if (s_) SB8b(wb_, k2_);                                               \
        __builtin_amdgcn_s_barrier();                                         \
        asm volatile("s_waitcnt lgkmcnt(0)" ::: "memory");                    \
        __builtin_amdgcn_s_setprio(1);                                        \
        MFMA16;                                                               \
        __builtin_amdgcn_s_setprio(0);                                        \
        if (s_) asm volatile("s_waitcnt vmcnt(6)" ::: "memory");              \
        else    asm volatile("s_waitcnt vmcnt(0)" ::: "memory");              \
        __builtin_amdgcn_s_barrier();                                         \
        rb_ = (rb_ == 2) ? 0 : rb_ + 1;                                      \
        wb_ = (wb_ == 2) ? 0 : wb_ + 1;                                      \
    }                                                                         \
    const int cb0 = n0 + wc * 64 + lc;                                        \
    const int rb0 = m0 + wr * 64 + quad * 4;

// Generic: C = A @ W^T + bias (+resid EPI=1, relu EPI=2). All bf16.
template<int EPI>
__global__ __launch_bounds__(512, 2) void gemm8(
    const u16* __restrict__ A, const u16* __restrict__ W,
    const u16* __restrict__ bias, const u16* __restrict__ resid,
    u16* __restrict__ C, int N, int K)
{
    GEMM8_PRE(A, W, K)
    GEMM8_LOOP
#pragma unroll
    for (int mq = 0; mq < 4; mq++) {
#pragma unroll
        for (int nq = 0; nq < 4; nq++) {
            const int cN = cb0 + nq * 16;
            const float bv = bf2f(bias[cN]);
#pragma unroll
            for (int i = 0; i < 4; i++) {
                const int rM = rb0 + mq * 16 + i;
                float v = acc[mq][nq][i] + bv;
                if (EPI == 1) v += bf2f(resid[(size_t)rM * N + cN]);
                if (EPI == 2) v = fmaxf(v, 0.0f);
                C[(size_t)rM * N + cN] = f2bf(v);
            }
        }
    }
}

// QKV on the gemm8 core (tier A): N=3072, K=1024, grid (64,12) = 768 blocks.
__global__ __launch_bounds__(512, 2) void gemm8_qkv(
    const u16* __restrict__ A, const u16* __restrict__ W,
    const u16* __restrict__ bias,
    u16* __restrict__ Qo, u16* __restrict__ Ko, u16* __restrict__ Vt)
{
    GEMM8_PRE(A, W, 1024)
    GEMM8_LOOP
    if (n0 < 1024) {
#pragma unroll
        for (int mq = 0; mq < 4; mq++)
#pragma unroll
            for (int nq = 0; nq < 4; nq++) {
                const int c = cb0 + nq * 16;
                const float bv = bf2f(bias[c]);
#pragma unroll
                for (int i = 0; i < 4; i++) {
                    const int r = rb0 + mq * 16 + i;
                    Qo[(size_t)r * 1024 + c] =
                        f2bf((acc[mq][nq][i] + bv) * QSCL);
                }
            }
    } else if (n0 < 2048) {
#pragma unroll
        for (int mq = 0; mq < 4; mq++)
#pragma unroll
            for (int nq = 0; nq < 4; nq++) {
                const int c = cb0 + nq * 16;
                const float bv = bf2f(bias[c]);
#pragma unroll
                for (int i = 0; i < 4; i++) {
                    const int r = rb0 + mq * 16 + i;
                    Ko[(size_t)r * 1024 + (c - 1024)] =
                        f2bf(acc[mq][nq][i] + bv);
                }
            }
    } else {
#pragma unroll
        for (int mq = 0; mq < 4; mq++)
#pragma unroll
            for (int nq = 0; nq < 4; nq++) {
                const int c = cb0 + nq * 16;
                const float bv = bf2f(bias[c]);
                const int cv = c - 2048;
                const int hh = cv >> 6, d = cv & 63;
                const int rbase = rb0 + mq * 16;
                const int bl = rbase >> 10, tt = rbase & 1023;
                short4v pk;
#pragma unroll
                for (int i = 0; i < 4; i++)
                    pk[i] = (short)f2bf(acc[mq][nq][i] + bv);
                *(short4v*)&Vt[((size_t)(bl * 16 + hh) * 64 + d) * 1024 + tt] = pk;
            }
    }
}

// ---------------------------------------------------------------------------
// gemm256 v3: 256x256 tile, BK=64, 512 threads = 8 waves (2M x 4N), per-wave
// 128x64. Double-buffered, K-HALF staged. NEW: all 24 fragment ds_reads for
// the tile are issued UP-FRONT (entire buffer is valid at tile start); the
// compiler inserts counted lgkmcnt before each MFMA cluster, so LDS reads
// overlap the matrix pipe (the 35%-util lockstep serialization removed).
// Barriers: 2/tile. Mid-tile barrier: every wave's kk0 frag reads complete
// before its M2 finishes (dataflow), so SAH(c_,0,t+2) issued after the
// barrier cannot race them. End-of-tile vmcnt(2): the 6 halves tile t+1
// needs are complete; only t+2's A-kk0 stays in flight.
// Swizzle (round-5, 0 conflicts): staging s_c=((tid&3)^((tid>>3)&3))<<3,
// read fsw=(quad^((lc>>1)&3))<<3.
// ---------------------------------------------------------------------------
#define GEMM256_PRE(Ag_, Wg_, Kg_)                                            \
    __shared__ __align__(16) u16 Ab2[2][2][8192];                             \
    __shared__ __align__(16) u16 Bb2[2][2][8192];                             \
    const u16* Ag = (Ag_); const u16* Wg = (Wg_); const int Kg = (Kg_);       \
    const int tid  = threadIdx.x;                                             \
    const int lane = tid & 63;                                                \
    const int lc   = lane & 15;                                               \
    const int quad = lane >> 4;                                               \
    const int w    = tid >> 6;                                                \
    const int wr   = w >> 2;                                                  \
    const int wc   = w & 3;                                                   \
    const int m0 = blockIdx.x * 256;                                          \
    const int n0 = blockIdx.y * 256;                                          \
    const int s_r = tid >> 2;                                                 \
    const int s_c = (((tid & 3) ^ ((tid >> 3) & 3)) << 3);                    \
    const int fsw = ((quad ^ ((lc >> 1) & 3)) << 3);                          \
    const int arow = wr * 128 + lc;                                           \
    const int brow = wc * 64 + lc;                                            \
    f32x4 acc[8][4] = {};                                                     \
    short8 afx[4][4];                                                         \
    short8 bfx[2][4];

#define SAH(buf, kk, tt) do {                                                 \
    GLD16(Ag + (size_t)(m0 + s_r) * Kg + (tt) * 64 + (kk) * 32 + s_c,         \
          &Ab2[buf][kk][tid * 8]);                                            \
    GLD16(Ag + (size_t)(m0 + 128 + s_r) * Kg + (tt) * 64 + (kk) * 32 + s_c,   \
          &Ab2[buf][kk][4096 + tid * 8]); } while (0)
#define SBH(buf, kk, tt) do {                                                 \
    GLD16(Wg + (size_t)(n0 + s_r) * Kg + (tt) * 64 + (kk) * 32 + s_c,         \
          &Bb2[buf][kk][tid * 8]);                                            \
    GLD16(Wg + (size_t)(n0 + 128 + s_r) * Kg + (tt) * 64 + (kk) * 32 + s_c,   \
          &Bb2[buf][kk][4096 + tid * 8]); } while (0)
#define LDA3(DST, buf, kk, MH) do { _Pragma("unroll")                         \
    for (int q_ = 0; q_ < 4; q_++)                                            \
        afx[DST][q_] = *(const short8*)                                       \
            &Ab2[buf][kk][(arow + ((MH) * 4 + q_) * 16) * 32 + fsw]; } while (0)
#define LDB3(DST, buf, kk) do { _Pragma("unroll")                             \
    for (int q_ = 0; q_ < 4; q_++)                                            \
        bfx[DST][q_] = *(const short8*)                                       \
            &Bb2[buf][kk][(brow + q_ * 16) * 32 + fsw]; } while (0)
#define MF3(AF, BF, MH) do { _Pragma("unroll")                                \
    for (int mq = 0; mq < 4; mq++) { _Pragma("unroll")                        \
    for (int nq = 0; nq < 4; nq++)                                            \
        acc[(MH) * 4 + mq][nq] = __builtin_amdgcn_mfma_f32_16x16x32_bf16(     \
            afx[AF][mq], bfx[BF][nq], acc[(MH) * 4 + mq][nq], 0, 0, 0); } } while (0)

#define GEMM256_LOOP                                                          \
    const int NT = Kg >> 6;                                                   \
    SAH(0, 0, 0); SBH(0, 0, 0); SAH(0, 1, 0); SBH(0, 1, 0);                   \
    if (NT > 1) SAH(1, 0, 1);                                                 \
    if (NT > 1) asm volatile("s_waitcnt vmcnt(2)" ::: "memory");              \
    else        asm volatile("s_waitcnt vmcnt(0)" ::: "memory");              \
    __builtin_amdgcn_s_barrier();                                             \
    for (int t = 0; t < NT; ++t) {                                            \
        const int c_ = t & 1, nx_ = c_ ^ 1;                                   \
        const bool s1_ = (t + 1 < NT), s2_ = (t + 2 < NT);                    \
        /* all 24 fragment reads up-front (buffer fully valid) */             \
        LDB3(0, c_, 0); LDA3(0, c_, 0, 0);                                    \
        LDA3(1, c_, 0, 1);                                                    \
        LDB3(1, c_, 1); LDA3(2, c_, 1, 0);                                    \
        LDA3(3, c_, 1, 1);                                                    \
        if (s1_) SBH(nx_, 0, t + 1);                                          \
        __builtin_amdgcn_s_setprio(1);                                        \
        MF3(0, 0, 0);                                                         \
        __builtin_amdgcn_s_setprio(0);                                        \
        if (s1_) SAH(nx_, 1, t + 1);                                          \
        __builtin_amdgcn_s_setprio(1);                                        \
        MF3(1, 0, 1);                                                         \
        __builtin_amdgcn_s_setprio(0);                                        \
        __builtin_amdgcn_s_barrier();   /* kk0 reads drained block-wide */    \
        if (s1_) SBH(nx_, 1, t + 1);                                          \
        __builtin_amdgcn_s_setprio(1);                                        \
        MF3(2, 1, 0);                                                         \
        __builtin_amdgcn_s_setprio(0);                                        \
        if (s2_) SAH(c_, 0, t + 2);                                           \
        __builtin_amdgcn_s_setprio(1);                                        \
        MF3(3, 1, 1);                                                         \
        __builtin_amdgcn_s_setprio(0);                                        \
        if (s2_) asm volatile("s_waitcnt vmcnt(2)" ::: "memory");             \
        else     asm volatile("s_waitcnt vmcnt(0)" ::: "memory");             \
        __builtin_amdgcn_s_barrier();                                         \
    }                                                                         \
    const int cb0 = n0 + wc * 64 + lc;                                        \
    const int rb0 = m0 + wr * 128 + quad * 4;

// Generic 256-tile: C = A @ W^T + bias (+resid EPI=1, relu EPI=2). All bf16.
template<int EPI>
__global__ __launch_bounds__(512, 2) void gemm256(
    const u16* __restrict__ A, const u16* __restrict__ W,
    const u16* __restrict__ bias, const u16* __restrict__ resid,
    u16* __restrict__ C, int N, int K)
{
    GEMM256_PRE(A, W, K)
    GEMM256_LOOP
#pragma unroll
    for (int mq = 0; mq < 8; mq++) {
#pragma unroll
        for (int nq = 0; nq < 4; nq++) {
            const int cN = cb0 + nq * 16;
            const float bv = bf2f(bias[cN]);
#pragma unroll
            for (int i = 0; i < 4; i++) {
                const int rM = rb0 + mq * 16 + i;
                float v = acc[mq][nq][i] + bv;
                if (EPI == 1) v += bf2f(resid[(size_t)rM * N + cN]);
                if (EPI == 2) v = fmaxf(v, 0.0f);
                C[(size_t)rM * N + cN] = f2bf(v);
            }
        }
    }
}

// ---------------------------------------------------------------------------
// Flash attention v4: Q pre-scaled by log2e so softmax is exp2-native.
// Block-uniform causal branch; row-sum via MFMA against a constant
// ones-column B fragment; P->bf16 via v_cvt_pk_bf16_f32; O-rescale skipped
// when no new max. Paired q-tiles (qt, 7-qt), dbuf K/V. Grid (4, nbh).
// ---------------------------------------------------------------------------
__global__ __launch_bounds__(256, 2) void attn_kernel(
    u16* __restrict__ QO, const u16* __restrict__ Ko,
    const u16* __restrict__ Vt, const float* __restrict__ kb, int b0)
{
    __shared__ __align__(16) u16 Qs[2 * 128 * 32];   // [kcd][qrow][32]
    __shared__ __align__(16) u16 Ks[2][2 * 64 * 32]; // dbuf [kcd][key][32]
    __shared__ __align__(16) u16 Vs[2][2 * 64 * 32]; // dbuf [kck][d][32]
    __shared__ __align__(16) u16 Ps[4][32 * 72];
    __shared__ float kba[1024];

    const int tid  = threadIdx.x;
    const int lane = tid & 63;
    const int w    = tid >> 6;
    const int lc   = lane & 15;
    const int quad = lane >> 4;
    const int bl = blockIdx.y >> 4;
    const int h  = blockIdx.y & 15;
    const int b  = b0 + bl;

    // constant B fragment: B[k][n] = (n==0) ? 1 : 0  ->  D[q][0] = sum_k P[q][k]
    short8 bsum;
    {
        const short ov = (lc == 0) ? (short)0x3F80 : (short)0;
#pragma unroll
        for (int j = 0; j < 8; j++) bsum[j] = ov;
    }

    // preload padding-bias column for this sequence
    *(f32x4*)&kba[tid * 4] = *(const f32x4*)&kb[b * 1024 + tid * 4];

    for (int p = 0; p < 2; p++) {
        const int qt = p ? 7 - (int)blockIdx.x : (int)blockIdx.x;

        // stage Q tile [kcd][128][32]
#pragma unroll
        for (int it = 0; it < 4; it++) {
            const int kcd = it >> 1, half = it & 1;
            const int r = half * 64 + (tid >> 2);
            const int c = kcd * 32 + (tid & 3) * 8;
            GLD16(&QO[((size_t)(b * 1024 + qt * 128 + r)) * 1024 + h * 64 + c],
                  &Qs[kcd * 4096 + half * 2048 + tid * 8]);
        }
        // stage kt=0 into buffer 0
        {
            const int rr = tid >> 2;
#pragma unroll
            for (int it = 0; it < 2; it++) {
                const int cc = it * 32 + (tid & 3) * 8;
                GLD16(&Ko[((size_t)(bl * 1024 + rr)) * 1024 + h * 64 + cc],
                      &Ks[0][it * 2048 + tid * 8]);
                GLD16(&Vt[((size_t)(bl * 16 + h) * 64 + rr) * 1024 + cc],
                      &Vs[0][it * 2048 + tid * 8]);
            }
        }
        __syncthreads();   // Q + K0/V0 (+ kba on p=0) ready

        short8 aq[2][2];
#pragma unroll
        for (int mt = 0; mt < 2; mt++)
#pragma unroll
            for (int kc = 0; kc < 2; kc++)
                aq[mt][kc] = *(const short8*)
                    &Qs[kc * 4096 + (w * 32 + mt * 16 + lc) * 32 + quad * 8];

        f32x4 o[2][4] = {};
        float m_i[2][4], l_i[2][4];
#pragma unroll
        for (int mt = 0; mt < 2; mt++)
#pragma unroll
            for (int i = 0; i < 4; i++) { m_i[mt][i] = -1e30f; l_i[mt][i] = 0.0f; }

        const int ktmax = 2 * qt + 2;
        for (int kt = 0; kt < ktmax; kt++) {
            const int cur = kt & 1;
            // prefetch kt+1 (overlaps with compute below; drained at barrier)
            if (kt + 1 < ktmax) {
                const int nxt = cur ^ 1;
                const int rr = tid >> 2;
#pragma unroll
                for (int it = 0; it < 2; it++) {
                    const int cc = it * 32 + (tid & 3) * 8;
                    GLD16(&Ko[((size_t)(bl * 1024 + (kt + 1) * 64 + rr)) * 1024 + h * 64 + cc],
                          &Ks[nxt][it * 2048 + tid * 8]);
                    GLD16(&Vt[((size_t)(bl * 16 + h) * 64 + rr) * 1024 + (kt + 1) * 64 + cc],
                          &Vs[nxt][it * 2048 + tid * 8]);
                }
            }

            // S = Q K^T  (already in log2 domain via Q pre-scale)
            short8 bk[4][2];
#pragma unroll
            for (int nt = 0; nt < 4; nt++)
#pragma unroll
                for (int kc = 0; kc < 2; kc++)
                    bk[nt][kc] = *(const short8*)
                        &Ks[cur][kc * 2048 + (nt * 16 + lc) * 32 + quad * 8];

            f32x4 s[2][4];
#pragma unroll
            for (int mt = 0; mt < 2; mt++)
#pragma unroll
                for (int nt = 0; nt < 4; nt++) {
                    f32x4 z = {};
#pragma unroll
                    for (int kc = 0; kc < 2; kc++)
                        z = __builtin_amdgcn_mfma_f32_16x16x32_bf16(
                            aq[mt][kc], bk[nt][kc], z, 0, 0, 0);
                    s[mt][nt] = z;
                }

            // padding bias (always) + causal mask (diagonal tiles only)
#pragma unroll
            for (int mt = 0; mt < 2; mt++)
#pragma unroll
                for (int nt = 0; nt < 4; nt++) {
                    const float kbv = kba[kt * 64 + nt * 16 + lc];
#pragma unroll
                    for (int i = 0; i < 4; i++) s[mt][nt][i] += kbv;
                }
            if (kt >= 2 * qt) {   // block-uniform branch
#pragma unroll
                for (int mt = 0; mt < 2; mt++) {
                    const int qg0 = qt * 128 + w * 32 + mt * 16 + quad * 4;
#pragma unroll
                    for (int nt = 0; nt < 4; nt++) {
                        const int kg = kt * 64 + nt * 16 + lc;
#pragma unroll
                        for (int i = 0; i < 4; i++)
                            if (kg > qg0 + i) s[mt][nt][i] = -1e30f;
                    }
                }
            }

            float al[2][4];
#pragma unroll
            for (int mt = 0; mt < 2; mt++) {
                float mnew[4];
#pragma unroll
                for (int i = 0; i < 4; i++) {
                    float rm = fmaxf(fmaxf(s[mt][0][i], s[mt][1][i]),
                                     fmaxf(s[mt][2][i], s[mt][3][i]));
                    rm = fmaxf(rm, __shfl_xor(rm, 1));
                    rm = fmaxf(rm, __shfl_xor(rm, 2));
                    rm = fmaxf(rm, __shfl_xor(rm, 4));
                    rm = fmaxf(rm, __shfl_xor(rm, 8));
                    const float mn = fmaxf(m_i[mt][i], rm);
                    al[mt][i] = exp2f(m_i[mt][i] - mn);
                    m_i[mt][i] = mn;
                    mnew[i] = mn;
                }
#pragma unroll
                for (int nt = 0; nt < 4; nt++)
#pragma unroll
                    for (int i = 0; i < 4; i++)
                        s[mt][nt][i] = exp2f(s[mt][nt][i] - mnew[i]);
                // P -> bf16 via packed cvt (rows quad*4+2j, quad*4+2j+1)
#pragma unroll
                for (int nt = 0; nt < 4; nt++) {
#pragma unroll
                    for (int i2 = 0; i2 < 2; i2++) {
                        unsigned int pk;
                        asm("v_cvt_pk_bf16_f32 %0, %1, %2"
                            : "=v"(pk)
                            : "v"(s[mt][nt][2 * i2]), "v"(s[mt][nt][2 * i2 + 1]));
                        Ps[w][(mt * 16 + quad * 4 + 2 * i2) * 72 + nt * 16 + lc] =
                            (u16)pk;
                        Ps[w][(mt * 16 + quad * 4 + 2 * i2 + 1) * 72 + nt * 16 + lc] =
                            (u16)(pk >> 16);
                    }
                }
            }
            int chg = 0;
#pragma unroll
            for (int mt = 0; mt < 2; mt++)
#pragma unroll
                for (int i = 0; i < 4; i++)
                    chg |= (al[mt][i] != 1.0f) ? 1 : 0;
            const int dor = __any(chg);   // wave-uniform

            // O = O*alpha + P @ V ; l-sum via MFMA against bsum
            short8 ap[2][2], bv2[4][2];
#pragma unroll
            for (int mt = 0; mt < 2; mt++)
#pragma unroll
                for (int kc = 0; kc < 2; kc++)
                    ap[mt][kc] = *(const short8*)
                        &Ps[w][(mt * 16 + lc) * 72 + kc * 32 + quad * 8];
#pragma unroll
            for (int nt = 0; nt < 4; nt++)
#pragma unroll
                for (int kc = 0; kc < 2; kc++)
                    bv2[nt][kc] = *(const short8*)
                        &Vs[cur][kc * 2048 + (nt * 16 + lc) * 32 + quad * 8];

            f32x4 ls[2] = {};
#pragma unroll
            for (int mt = 0; mt < 2; mt++)
#pragma unroll
                for (int kc = 0; kc < 2; kc++)
                    ls[mt] = __builtin_amdgcn_mfma_f32_16x16x32_bf16(
                        ap[mt][kc], bsum, ls[mt], 0, 0, 0);

#pragma unroll
            for (int mt = 0; mt < 2; mt++)
#pragma unroll
                for (int nt = 0; nt < 4; nt++) {
                    f32x4 oo = o[mt][nt];
                    if (dor) {
#pragma unroll
                        for (int i = 0; i < 4; i++) oo[i] *= al[mt][i];
                    }
#pragma unroll
                    for (int kc = 0; kc < 2; kc++)
                        oo = __builtin_amdgcn_mfma_f32_16x16x32_bf16(
                            ap[mt][kc], bv2[nt][kc], oo, 0, 0, 0);
                    o[mt][nt] = oo;
                }
#pragma unroll
            for (int mt = 0; mt < 2; mt++)
#pragma unroll
                for (int i = 0; i < 4; i++)
                    l_i[mt][i] = l_i[mt][i] * al[mt][i] + ls[mt][i];

            __syncthreads();   // prefetch drained; buffers safe to swap
        }

        // write O in place of Q (exclusive slice); true l lives in lc==0 lanes
#pragma unroll
        for (int mt = 0; mt < 2; mt++)
#pragma unroll
            for (int i = 0; i < 4; i++) {
                const float lv = __shfl(l_i[mt][i], (lane & 48));
                const float inv = lv > 0.0f ? 1.0f / lv : 0.0f;
#pragma unroll
                for (int nt = 0; nt < 4; nt++) {
                    const int r = qt * 128 + w * 32 + mt * 16 + quad * 4 + i;
                    const int d = nt * 16 + lc;
                    QO[((size_t)(b * 1024 + r)) * 1024 + h * 64 + d] =
                        f2bf(o[mt][nt][i] * inv);
                }
            }
    }
}

// ---------------------------------------------------------------------------
// LayerNorm, one block/row, biased variance, eps=1e-12.
// ---------------------------------------------------------------------------
template<int IN16, int OUTSEL>
__global__ __launch_bounds__(256) void ln_kernel(
    const void* __restrict__ yv, const void* __restrict__ w,
    const void* __restrict__ bb, void* __restrict__ o, long o_row0,
    const int* __restrict__ flags)
{
    const int row = blockIdx.x;
    const int tid = threadIdx.x;
    const int inf32 = flags[0];
    float x0, x1, x2, x3;
    if (IN16) {
        const u16* p = (const u16*)yv + (size_t)row * 1024 + tid * 4;
        short4v v = *(const short4v*)p;
        x0 = bf2f((u16)v[0]); x1 = bf2f((u16)v[1]);
        x2 = bf2f((u16)v[2]); x3 = bf2f((u16)v[3]);
    } else {
        const float* p = (const float*)yv + (size_t)row * 1024 + tid * 4;
        f32x4 v = *(const f32x4*)p;
        x0 = v[0]; x1 = v[1]; x2 = v[2]; x3 = v[3];
    }
    float s = x0 + x1 + x2 + x3;
    float q = x0 * x0 + x1 * x1 + x2 * x2 + x3 * x3;
#pragma unroll
    for (int off = 32; off; off >>= 1) {
        s += __shfl_xor(s, off);
        q += __shfl_xor(q, off);
    }
    __shared__ float sm[8];
    const int lane = tid & 63, wv = tid >> 6;
    if (lane == 0) { sm[wv] = s; sm[4 + wv] = q; }
    __syncthreads();
    const float ts = sm[0] + sm[1] + sm[2] + sm[3];
    const float tq = sm[4] + sm[5] + sm[6] + sm[7];
    const float mean = ts * (1.0f / 1024.0f);
    float var = tq * (1.0f / 1024.0f) - mean * mean;
    if (var < 0.0f) var = 0.0f;
    const float rinv = rsqrtf(var + 1e-12f);

    const size_t obase = ((size_t)o_row0 + row) * 1024 + tid * 4;
#pragma unroll
    for (int j = 0; j < 4; j++) {
        const int c = tid * 4 + j;
        float xv = (j == 0) ? x0 : (j == 1) ? x1 : (j == 2) ? x2 : x3;
        float v = ldx(w, c, inf32) * ((xv - mean) * rinv) + ldx(bb, c, inf32);
        if (OUTSEL && inf32) ((float*)o)[obase + j] = v;
        else                 ((u16*)o)[obase + j] = f2bf(v);
    }
}

// ---------------------------------------------------------------------------
extern "C" void kernel_launch(void* const* d_in, const int* in_sizes, int n_in,
                              void* d_out, int out_size, void* d_ws, size_t ws_size,
                              hipStream_t stream)
{
    const void* x     = d_in[0];
    const void* in_w  = d_in[1];
    const void* in_b  = d_in[2];
    const void* out_w = d_in[3];
    const void* out_b = d_in[4];
    const void* fc1_w = d_in[5];
    const void* fc1_b = d_in[6];
    const void* fc2_w = d_in[7];
    const void* fc2_b = d_in[8];
    const void* ln1w  = d_in[9];
    const void* ln1b  = d_in[10];
    const void* ln2w  = d_in[11];
    const void* ln2b  = d_in[12];
    const void* pad   = d_in[13];
    u16* outp = (u16*)d_out;
    char* ws = (char*)d_ws;
    dim3 blk(256);
    dim3 blk8(512);

    const size_t MB = 1024 * 1024;
    const bool bigWS = ws_size >= (105 * MB + 64 * 1024);

    if (bigWS) {
        // Tier A layout:
        //  0-16  xb -> x1        16-22 w1b (dead after qkv) \
        //  22-24 wob (dead after proj)  24-32 f1b (dead after fc1) } -> y2 16-32
        //  32-40 f2b   40-41 biases     41-57 Ko    57-73 Vt
        //  73-89 y1    41-105 h (FF)    105+ flags / kbias
        u16*   xb   = (u16*)(ws + 0);
        u16*   x1   = (u16*)(ws + 0);
        u16*   w1b  = (u16*)(ws + 16 * MB);
        u16*   wob  = (u16*)(ws + 22 * MB);
        u16*   f1b  = (u16*)(ws + 24 * MB);
        u16*   f2b  = (u16*)(ws + 32 * MB);
        u16*   inbb = (u16*)(ws + 40 * MB);
        u16*   outbb= (u16*)(ws + 40 * MB + 8192);
        u16*   f1bb = (u16*)(ws + 40 * MB + 16384);
        u16*   f2bb = (u16*)(ws + 40 * MB + 24576);
        u16*   Ko   = (u16*)(ws + 41 * MB);
        u16*   Vt   = (u16*)(ws + 57 * MB);
        u16*   y1   = (u16*)(ws + 73 * MB);
        u16*   h    = (u16*)(ws + 41 * MB);
        u16*   y2   = (u16*)(ws + 16 * MB);
        int*   flags  = (int*)(ws + 105 * MB);
        int*   flagsA = (int*)(ws + 105 * MB + 32);
        float* kbias  = (float*)(ws + 105 * MB + 64);

        probe_kernel<<<dim3(1), dim3(64), 0, stream>>>(x, pad, flags, flagsA);
        mask_to_bias<<<dim3(32), blk, 0, stream>>>(pad, kbias, flags);
        conv_all<<<dim3(10245), blk, 0, stream>>>(
            x, in_w, out_w, fc1_w, fc2_w, in_b, out_b, fc1_b, fc2_b,
            xb, w1b, wob, f1b, f2b, inbb, outbb, f1bb, f2bb, flags);

        // qkv on the gemm8 core: [8192,3072] K=1024, 768 blocks = 3 rounds
        gemm8_qkv<<<dim3(64, 12), blk8, 0, stream>>>(
            xb, w1b, inbb, outp, Ko, Vt);
        attn_kernel<<<dim3(4, 128), blk, 0, stream>>>(outp, Ko, Vt, kbias, 0);
        // out-proj: y1 = attn @ wob^T + outbb + xb   [8192,1024] K=1024
        gemm8<1><<<dim3(64, 4), blk8, 0, stream>>>(
            outp, wob, outbb, xb, y1, 1024, 1024);
        ln_kernel<1, 0><<<dim3(8192), blk, 0, stream>>>(y1, ln1w, ln1b, x1, 0, flags);
        // fc1: h = relu(x1 @ f1b^T + f1bb)   [8192,4096] K=1024
        gemm256<2><<<dim3(32, 16), blk8, 0, stream>>>(
            x1, f1b, f1bb, nullptr, h, 4096, 1024);
        // fc2: y2 = h @ f2b^T + f2bb + x1    [8192,1024] K=4096
        gemm8<1><<<dim3(64, 4), blk8, 0, stream>>>(
            h, f2b, f2bb, x1, y2, 1024, 4096);
        ln_kernel<1, 1><<<dim3(8192), blk, 0, stream>>>(y2, ln2w, ln2b, d_out, 0, flags);
    } else {
        // Tier C: quartered, 12.6 MB workspace
        u16*   Ko    = (u16*)(ws + 0);
        u16*   Vt    = (u16*)(ws + 4 * MB);
        u16*   y1h   = (u16*)(ws + 0);
        float* acc   = (float*)(ws + 0);
        u16*   hc    = (u16*)(ws + 8 * MB);
        int*   flags  = (int*)(ws + 12 * MB);
        int*   flagsA = (int*)(ws + 12 * MB + 32);
        float* kbias  = (float*)(ws + 12 * MB + 64);

        probe_kernel<<<dim3(1), dim3(64), 0, stream>>>(x, pad, flags, flagsA);
        mask_to_bias<<<dim3(32), blk, 0, stream>>>(pad, kbias, flags);

        for (int q = 0; q < 4; q++) {
            const long r0 = (long)q * 2048;
            gemm_qkv<<<dim3(16, 24), blk, 0, stream>>>(
                x, r0, in_w, in_b, outp, Ko, Vt, flags);
            attn_kernel<<<dim3(4, 32), blk, 0, stream>>>(
                outp, Ko, Vt, kbias, q * 2);
        }
        for (int hf = 0; hf < 2; hf++) {
            const long r0 = (long)hf * 4096;
            gemm_bt<1><<<dim3(32, 8), blk, 0, stream>>>(
                outp, 0, r0, out_w, 0, out_b, 0, x, 1, r0,
                y1h, 0, 1024, 1024, 1024, flags);
            ln_kernel<1, 0><<<dim3(4096), blk, 0, stream>>>(
                y1h, ln1w, ln1b, outp, r0, flags);
        }
        for (int q = 3; q >= 0; q--) {
            const long r0 = (long)q * 2048;
            for (int c = 0; c < 4; c++) {
                gemm_bt<2><<<dim3(16, 8), blk, 0, stream>>>(
                    outp, 0, r0, fc1_w, (long)c * 1024 * 1024, fc1_b, (long)c * 1024,
                    nullptr, 0, 0, hc, 0, 1024, 1024, 1024, flags);
                gemm_accf32<<<dim3(16, 8), blk, 0, stream>>>(
                    hc, fc2_w, (long)c * 1024, fc2_b, outp, r0,
                    acc, 4096, c == 0, flags);
            }
            ln_kernel<0, 1><<<dim3(2048), blk, 0, stream>>>(
                acc, ln2w, ln2b, d_out, r0, flags);
        }
    }
}